// Round 6
// baseline (378.328 us; speedup 1.0000x reference)
//
#include <hip/hip_runtime.h>
#include <hip/hip_bf16.h>
#include <math.h>

#define B_  32
#define T_  2048
#define D_  512
#define V_  1024
#define K_  3

typedef __attribute__((ext_vector_type(8))) short    short8;
typedef __attribute__((ext_vector_type(4))) float    floatx4;
typedef __attribute__((ext_vector_type(2))) long     longx2;   // 16 B paired fp8 frags
typedef __attribute__((ext_vector_type(2))) _Float16 half2v;   // fp16 pair

#define SCALE_H0 256.0f        // hidden0 fp8 scale (conv1 input)
#define SCALE_A  64.0f         // H1 activation fp8 scale (conv2 input)
#define SCALE_W  16.0f         // weight fp8 scale (both convs)
#define INV1 (1.0f/(SCALE_H0*SCALE_W))
#define INV2 (1.0f/(SCALE_A*SCALE_W))

// ---- output flat offsets (elements, fp32) ----
#define OFF0 0        // global_rate      [32]
#define OFF1 32       // summary_state    [32*512]
#define OFF2 16416    // residual_mean    [32]
#define OFF3 16448    // residual_var     [32]
#define OFF4 16480    // coverage         [32]
#define OFF5 16512    // mask             [32*2048]
#define OFF6 82048    // logdur           [32*2048]
#define OFF7 147584   // ref_residual     [32*2048]
#define OFF8 213120   // attn             [32*2048]
#define OFF9 278656   // prompt_role_fit  [32*2048]
#define OFF10 344192  // coeff_norm       [32]

// ---- workspace byte offsets (end 35,684,608 B < proven 36.34 MB) ----
// W1P/W2P are 48 K-steps * 16 KB + 2 PAD steps (32 KB) so the convs'
// branch-free depth-2 prefetch can over-read harmlessly.
#define WS_RR     0          // fp32 [32][2048]              262144 B
#define WS_SUP    262144     // fp32 [32]                       128 B
#define WS_PSUM   262272     // fp32 [32][512]                65536 B
#define WS_PSUMSQ 327808     // fp32 [32][512]                65536 B
#define WS_W1P    393344     // fp8 pair-packed conv1 w      819200 B (50 steps)
#define WS_W2P    1212544    // fp8 pair-packed conv2 w      819200 B (50 steps)
#define WS_H1     2031744    // fp8  [32][2050][512]       33587200 B
#define WS_S1     35618944   // fp32 [32][512] mlp hidden     65536 B
#define WS_NRM    35684480   // fp32 [32] coeff_norm accum      128 B

__device__ __forceinline__ float clampf(float v, float lo, float hi) {
    v = (v > lo) ? v : lo;
    return (v < hi) ? v : hi;
}
// NOTE: keep gelu_exact (erff) in the conv epilogues. The inlined tanh-form
// gelu_fast triggered accumulator spill-to-scratch in R8/R9/R10 (FETCH/WRITE
// blew up 10x, conv1g 130 -> 366 us). erff's call structure keeps acc
// register-resident. Do not "optimize" this again without checking WRITE_SIZE.
__device__ __forceinline__ float gelu_exact(float v) {
    return 0.5f * v * (1.0f + erff(v * 0.70710678118654752440f));
}
__device__ __forceinline__ unsigned char f2fp8(float x) {
    int v = __builtin_amdgcn_cvt_pk_fp8_f32(x, x, 0, false);
    return (unsigned char)(v & 0xFF);
}
__device__ __forceinline__ int pk4fp8(float a, float b, float c, float d) {
    int p0 = __builtin_amdgcn_cvt_pk_fp8_f32(a, b, 0, false);
    int p1 = __builtin_amdgcn_cvt_pk_fp8_f32(c, d, 0, false);
    return (p1 << 16) | (p0 & 0xFFFF);
}

__device__ __forceinline__ float block_reduce_sum(float v, float* red, int tid) {
    __syncthreads();
    red[tid] = v;
    __syncthreads();
    for (int s = 128; s > 0; s >>= 1) {
        if (tid < s) red[tid] += red[tid + s];
        __syncthreads();
    }
    float r = red[0];
    __syncthreads();
    return r;
}

// ---------------------------------------------------------------------------
// Kernel 1: MERGED init — blocks 0..31: per-batch stats (histogram-select
//   exact median + T-wise outputs); blocks 32..63: LDS-transpose weight
//   prepack + psum/H1-pad zeroing.
// Pair-packed weight layout: 16 B per (K-step s, pair-group pg, lane):
//   byte addr = ((s*16 + pg)*64 + lane)*16 + (ntg&1)*8, pg = ntg>>1.
// ---------------------------------------------------------------------------
#define NB 2048
#define HLO (-9.3f)
#define HSC ((float)NB / 10.05f)     // range [-9.3, 0.75]
#define WLS 1544                     // LDS row stride (1536 + 8 pad)
__global__ __launch_bounds__(256) void init_kernel(
    const float* __restrict__ dur, const float* __restrict__ maskp,
    const float* __restrict__ w1, const float* __restrict__ w2,
    unsigned char* __restrict__ W1p, unsigned char* __restrict__ W2p,
    unsigned char* __restrict__ H1buf,
    float* __restrict__ rr_ws, float* __restrict__ sup_ws,
    float* __restrict__ psum, float* __restrict__ out)
{
    int tid = threadIdx.x;

    if (blockIdx.x >= 32) {
        // ---------------- prepack part (LDS transpose) ----------------
        __shared__ unsigned char Wl[2 * 16 * WLS];   // 49408 B
        int ntg = blockIdx.x - 32;                   // 0..31 (16-col group)
        int lane = tid & 63, wave = tid >> 6;

        #pragma unroll
        for (int ws = 0; ws < 2; ++ws) {
            const float* wsrc = (ws ? w2 : w1) + (size_t)ntg * 16 * 1536;
            for (int i = tid; i < 6144; i += 256) {      // 16 cols x 1536 f
                float4 v = ((const float4*)wsrc)[i];
                int col_local = i / 384;                 // 384 float4 per col
                int pos = (i % 384) * 4;
                int word = pk4fp8(v.x * SCALE_W, v.y * SCALE_W,
                                  v.z * SCALE_W, v.w * SCALE_W);
                *(int*)(&Wl[(ws * 16 + col_local) * WLS + pos]) = word;
            }
        }
        __syncthreads();

        int cl = lane & 15, qq = lane >> 4;
        int pg = ntg >> 1, half = ntg & 1;
        #pragma unroll
        for (int ws = 0; ws < 2; ++ws) {
            unsigned char* dst = ws ? W2p : W1p;
            for (int s = wave; s < 48; s += 4) {
                int ci = s & 15, k = s >> 4;
                const unsigned char* row = &Wl[(ws * 16 + cl) * WLS];
                int kin = ci * 32 + qq * 8;
                unsigned char bb[8];
                #pragma unroll
                for (int e = 0; e < 8; ++e)
                    bb[e] = row[(kin + e) * 3 + k];
                *(double*)(dst + (((size_t)(s * 16 + pg) * 64 + lane) * 16
                                  + half * 8)) = *(double*)bb;
            }
        }

        // zeroing: 32 blocks x 256 threads x 4 = 32768 elems each array
        int pid2 = ntg * 256 + tid;
        #pragma unroll
        for (int j = 0; j < 4; ++j) {
            int idx = pid2 + j * 8192;
            psum[idx] = 0.0f;                      // psum + psumsq contiguous
            int b = idx >> 10;
            int r = (idx >> 9) & 1;
            int d = idx & 511;
            H1buf[((size_t)b * 2050 + r) * 512 + d] = 0;
        }
        return;
    }

    // ---------------- stats part ----------------
    __shared__ int   hist[NB];
    __shared__ int   csum[256];
    __shared__ float red[256];
    __shared__ float cand[128];
    __shared__ float nsh, medsh;
    __shared__ int   sh_tb, sh_cb, sh_candn;

    int b = blockIdx.x;
    const float* durb = dur + (size_t)b * T_;
    const float* mkb  = maskp + (size_t)b * T_;

    float ld[8], mk[8];
    int   bn[8];
    float cnt = 0.0f;
    #pragma unroll
    for (int i = 0; i < 8; ++i) hist[tid * 8 + i] = 0;
    __syncthreads();
    #pragma unroll
    for (int i = 0; i < 8; ++i) {
        int t = tid + i * 256;
        float m = clampf(mkb[t], 0.0f, 1.0f);
        float dv = durb[t];
        dv = (dv >= 1e-4f) ? dv : 1e-4f;
        float l = logf(dv) * m;
        ld[i] = l; mk[i] = m;
        int bin = (int)((l - HLO) * HSC);
        bin = (bin < 0) ? 0 : ((bin > NB - 1) ? NB - 1 : bin);
        bn[i] = bin;
        if (m > 0.5f) { cnt += 1.0f; atomicAdd(&hist[bin], 1); }
    }
    float n = block_reduce_sum(cnt, red, tid);   // barriers make hist visible
    if (tid == 0) { nsh = n; sh_candn = 0; medsh = 0.0f; }

    // chunk sums + inclusive scan (Hillis-Steele)
    {
        int cs = 0;
        #pragma unroll
        for (int i = 0; i < 8; ++i) cs += hist[tid * 8 + i];
        csum[tid] = cs;
        __syncthreads();
        for (int off = 1; off < 256; off <<= 1) {
            int v = (tid >= off) ? csum[tid - off] : 0;
            __syncthreads();
            csum[tid] += v;
            __syncthreads();
        }
    }
    int ni = (int)(n + 0.5f);
    int k  = (ni > 0) ? ((ni - 1) >> 1) : 0;     // 0-indexed lower-median rank
    {
        int prevIncl = (tid > 0) ? csum[tid - 1] : 0;
        if (ni > 0 && k >= prevIncl && k < csum[tid]) {   // unique owner thread
            int cum = prevIncl, tb = tid * 8;
            #pragma unroll
            for (int i = 0; i < 8; ++i) {
                int c = hist[tid * 8 + i];
                if (k < cum + c) { tb = tid * 8 + i; break; }
                cum += c;
            }
            sh_tb = tb; sh_cb = cum;
        }
    }
    __syncthreads();
    // collect candidates in target bin
    if (ni > 0) {
        int tb = sh_tb;
        #pragma unroll
        for (int i = 0; i < 8; ++i) {
            if (mk[i] > 0.5f && bn[i] == tb) {
                int p = atomicAdd(&sh_candn, 1);
                if (p < 128) cand[p] = ld[i];
            }
        }
    }
    __syncthreads();
    if (tid == 0 && ni > 0) {
        int m = k - sh_cb;
        int cn = (sh_candn < 128) ? sh_candn : 128;
        float best = cand[0];
        for (int i = 0; i < cn; ++i) {
            int rank = 0;
            for (int j = 0; j < cn; ++j)
                rank += (cand[j] < cand[i]) || (cand[j] == cand[i] && j < i);
            if (rank == m) { best = cand[i]; break; }
        }
        medsh = best;
    }
    __syncthreads();
    float med = (ni > 0) ? medsh : 0.0f;
    med = clampf(med, -20.0f, 20.0f);

    float denom = (n > 1.0f) ? n : 1.0f;
    float rv[8];
    float ssum = 0.0f;
    #pragma unroll
    for (int i = 0; i < 8; ++i) { rv[i] = (ld[i] - med) * mk[i]; ssum += rv[i]; }
    float rsum = block_reduce_sum(ssum, red, tid);
    float rm = clampf(rsum / denom, -40.0f, 40.0f);

    float vsum_l = 0.0f;
    #pragma unroll
    for (int i = 0; i < 8; ++i) { float dd = rv[i] - rm; vsum_l += dd * dd * mk[i]; }
    float vsum = block_reduce_sum(vsum_l, red, tid);
    float var = clampf(vsum / denom, 1e-4f, 1e4f);

    float inv_sup = 1.0f / denom;
    #pragma unroll
    for (int i = 0; i < 8; ++i) {
        int t = tid + i * 256;
        size_t o = (size_t)b * T_ + t;
        out[OFF5 + o] = mk[i];
        out[OFF6 + o] = ld[i];
        out[OFF7 + o] = rv[i];
        out[OFF8 + o] = mk[i] * inv_sup;
        out[OFF9 + o] = rm * mk[i];
        rr_ws[o] = rv[i];
    }
    if (tid == 0) {
        out[OFF0 + b] = med;
        out[OFF2 + b] = rm;
        out[OFF3 + b] = var;
        float cov = n * (1.0f / (float)T_);
        out[OFF4 + b] = (cov > 0.05f) ? cov : 0.05f;
        sup_ws[b] = n;
    }
}

// ---------------------------------------------------------------------------
// Kernel 2: conv1 gather-GEMM, fp8 MFMA. BM=64 x 512 (two 256-col halves,
//   acc[4][4]). Pair-packed weights (one 16 B dwordx4 load covers two nt
//   fragments) + branch-free 4-phase register rotation, prefetch distance 2.
//   PROVEN R1: 195 -> ~58 us (~86% of the 50 us MFMA-issue floor).
//   launch_bounds MUST stay (256,3): (256,4) forces a 64-VGPR allocation
//   on this compiler (measured twice: R8, R12) -> accumulator spill ->
//   100+ MB scratch WRITE_SIZE, 2x slower. (256,3) = 76 VGPR, no scratch.
// ---------------------------------------------------------------------------
#define H0S 520
__global__ __launch_bounds__(256, 3) void conv1g_kernel(
    const int* __restrict__ ids, const float* __restrict__ rr,
    const float* __restrict__ emb,
    const float* __restrict__ aux_w, const float* __restrict__ aux_b,
    const unsigned char* __restrict__ W1p, const float* __restrict__ bias1,
    unsigned char* __restrict__ H1buf)
{
    __shared__ __align__(16) unsigned char H0s[66 * H0S];   // 34320 B
    __shared__ int   lid[66];
    __shared__ float lrr[66];

    int tile = blockIdx.x;          // 0..31
    int b    = blockIdx.y;          // 0..31
    int r0   = tile << 6;
    int tid  = threadIdx.x;
    int wave = tid >> 6, lane = tid & 63;
    int q = lane >> 4, m16 = lane & 15;

    if (tid < 66) {
        int t = r0 - 2 + tid;
        bool v = (t >= 0);
        lid[tid] = v ? ids[b * T_ + t] : -1;
        lrr[tid] = v ? rr[(size_t)b * T_ + t] : 0.0f;
    }
    __syncthreads();

    {   // gather hidden0 -> fp8 LDS
        int c4 = tid & 127;
        float4 aw = *(const float4*)(aux_w + c4 * 4);
        float4 ab = *(const float4*)(aux_b + c4 * 4);
        int rbase = tid >> 7;
        for (int j = 0; j < 33; ++j) {
            int row = rbase + j * 2;
            int id = lid[row];
            int word = 0;
            if (id >= 0) {
                float vr = lrr[row];
                float4 e = *(const float4*)(emb + (size_t)id * D_ + c4 * 4);
                word = pk4fp8((e.x + vr * aw.x + ab.x) * SCALE_H0,
                              (e.y + vr * aw.y + ab.y) * SCALE_H0,
                              (e.z + vr * aw.z + ab.z) * SCALE_H0,
                              (e.w + vr * aw.w + ab.w) * SCALE_H0);
            }
            *(int*)(&H0s[row * H0S + c4 * 4]) = word;
        }
    }
    __syncthreads();

    unsigned char* Ob = H1buf + ((size_t)b * 2050 + 2 + r0) * 512;

    // one K-step of MFMAs against a loaded weight pair (FR0 = nt{0,1}, FR1 = nt{2,3})
#define CONV1_PHASE(FR0, FR1, SS)                                              \
    {   int k1 = (SS) >> 4, ci = (SS) & 15;                                    \
        _Pragma("unroll")                                                      \
        for (int mt = 0; mt < 4; ++mt) {                                       \
            long afr = *(const long*)(&H0s[(mt * 16 + m16 + k1) * H0S + ci * 32 + q * 8]); \
            acc[mt][0] = __builtin_amdgcn_mfma_f32_16x16x32_fp8_fp8(afr, FR0[0], acc[mt][0], 0, 0, 0); \
            acc[mt][1] = __builtin_amdgcn_mfma_f32_16x16x32_fp8_fp8(afr, FR0[1], acc[mt][1], 0, 0, 0); \
            acc[mt][2] = __builtin_amdgcn_mfma_f32_16x16x32_fp8_fp8(afr, FR1[0], acc[mt][2], 0, 0, 0); \
            acc[mt][3] = __builtin_amdgcn_mfma_f32_16x16x32_fp8_fp8(afr, FR1[1], acc[mt][3], 0, 0, 0); \
        } }

    #pragma unroll
    for (int nh = 0; nh < 2; ++nh) {
        floatx4 acc[4][4];
        #pragma unroll
        for (int i = 0; i < 4; ++i)
            #pragma unroll
            for (int j = 0; j < 4; ++j)
                acc[i][j] = (floatx4){0.f, 0.f, 0.f, 0.f};

        // pair-group bases: pg0 covers nt{0,1}, pg0+1 covers nt{2,3}
        const longx2* wp0 = (const longx2*)W1p
                          + ((size_t)(0 * 16 + nh * 8 + wave * 2 + 0) * 64 + lane);
        const longx2* wp1 = wp0 + 64;
        // K-step stride = 16 pair-groups * 64 lanes = 1024 longx2

        longx2 fA0 = wp0[0],                  fA1 = wp1[0];
        longx2 fB0 = wp0[(size_t)1 * 1024],   fB1 = wp1[(size_t)1 * 1024];
        longx2 fC0, fC1, fD0, fD1;

        #pragma unroll 1
        for (int s = 0; s < 48; s += 4) {
            fC0 = wp0[(size_t)(s + 2) * 1024]; fC1 = wp1[(size_t)(s + 2) * 1024];
            CONV1_PHASE(fA0, fA1, s)
            fD0 = wp0[(size_t)(s + 3) * 1024]; fD1 = wp1[(size_t)(s + 3) * 1024];
            CONV1_PHASE(fB0, fB1, s + 1)
            fA0 = wp0[(size_t)(s + 4) * 1024]; fA1 = wp1[(size_t)(s + 4) * 1024]; // pads at 48/49
            CONV1_PHASE(fC0, fC1, s + 2)
            fB0 = wp0[(size_t)(s + 5) * 1024]; fB1 = wp1[(size_t)(s + 5) * 1024];
            CONV1_PHASE(fD0, fD1, s + 3)
        }

        #pragma unroll
        for (int mt = 0; mt < 4; ++mt) {
            #pragma unroll
            for (int nt = 0; nt < 4; ++nt) {
                int col = nh * 256 + wave * 64 + nt * 16 + m16;
                float bsv = bias1[col];
                #pragma unroll
                for (int r = 0; r < 4; ++r) {
                    int row = mt * 16 + q * 4 + r;
                    float v = gelu_exact(acc[mt][nt][r] * INV1 + bsv) * SCALE_A;
                    Ob[(size_t)row * 512 + col] = f2fp8(v);
                }
            }
        }
    }
#undef CONV1_PHASE
}

// ---------------------------------------------------------------------------
// Kernel 3: conv2 (fp8 MFMA) + gelu + LN + masked column sums.
//   R6: LITERAL clone of conv1's proven K-loop. BM=64, 1024 blocks, two
//   sequential 256-col passes (nh=0,1), acc[4][4] (64 AGPR) per pass,
//   2 load streams/phase (32 B per 16 MFMA — same load:MFMA ratio as conv1).
//   Half-A survives across pass B as 32 fp16x2 VGPRs (post-gelu packed) —
//   solves R4's 128-AGPR spill without LDS round-trip. fp16 err ~5e-4 <<
//   0.0078 absmax budget (fp8-dominated).
//   HISTORY: R2 (array bufs) null VGPR=116; R5 (named scalar bufs, 4-stream
//   BM=32) null VGPR=116 — rotation gets sunk in the 4-stream/mt=2 shape.
//   conv1's 2-stream/mt=4 shape is the only form measured at 86%-of-floor.
//   VERIFY: dur ~70-85 us expected. TRIPWIRE: WRITE_SIZE >> 8 MB => aPk or
//   buffers spilled => revert to R5 form; dur > 134 us => structure
//   hypothesis falsified too.
// ---------------------------------------------------------------------------
#define H1S 520
__global__ __launch_bounds__(256, 2) void conv2ln_kernel(
    const unsigned char* __restrict__ H1buf, const unsigned char* __restrict__ W2p,
    const float* __restrict__ bias2,
    const float* __restrict__ ln_g, const float* __restrict__ ln_b,
    const float* __restrict__ maskp,
    float* __restrict__ psum, float* __restrict__ psumsq)
{
    __shared__ __align__(16) unsigned char H1s[66 * H1S];   // 34320 B
    __shared__ float mrow[64];
    __shared__ float part[64][4][2];
    __shared__ float tot[64][2];
    __shared__ float colsum[512][2];

    int tile = blockIdx.x;          // 0..31
    int b    = blockIdx.y;          // 0..31
    int r0   = tile << 6;           // output rows r0..r0+63
    int tid  = threadIdx.x;
    int wave = tid >> 6, lane = tid & 63;
    int q = lane >> 4, m16 = lane & 15;

    // stage H1 rows r0..r0+65 (2-row causal halo; H1buf rows pre-shifted +2)
    const unsigned char* src = H1buf + ((size_t)b * 2050 + r0) * 512;
    for (int g = tid; g < 66 * 32; g += 256) {
        int row = g >> 5, h = g & 31;
        *(float4*)(&H1s[row * H1S + h * 16]) = *(const float4*)(src + (size_t)row * 512 + h * 16);
    }
    if (tid < 64)
        mrow[tid] = clampf(maskp[(size_t)b * T_ + r0 + tid], 0.0f, 1.0f);
    __syncthreads();

    half2v aPk[4][4][2];    // half-A post-gelu, fp16-packed (32 VGPR)

#define C2_PHASE(FR0, FR1, SS)                                                 \
    {   int k2 = (SS) >> 4, ci = (SS) & 15;                                    \
        _Pragma("unroll")                                                      \
        for (int mt = 0; mt < 4; ++mt) {                                       \
            long afr = *(const long*)(&H1s[(mt * 16 + m16 + k2) * H1S + ci * 32 + q * 8]); \
            acc[mt][0] = __builtin_amdgcn_mfma_f32_16x16x32_fp8_fp8(afr, FR0[0], acc[mt][0], 0, 0, 0); \
            acc[mt][1] = __builtin_amdgcn_mfma_f32_16x16x32_fp8_fp8(afr, FR0[1], acc[mt][1], 0, 0, 0); \
            acc[mt][2] = __builtin_amdgcn_mfma_f32_16x16x32_fp8_fp8(afr, FR1[0], acc[mt][2], 0, 0, 0); \
            acc[mt][3] = __builtin_amdgcn_mfma_f32_16x16x32_fp8_fp8(afr, FR1[1], acc[mt][3], 0, 0, 0); \
        } }

    floatx4 acc[4][4];
    #pragma unroll
    for (int nh = 0; nh < 2; ++nh) {
        #pragma unroll
        for (int i = 0; i < 4; ++i)
            #pragma unroll
            for (int j = 0; j < 4; ++j)
                acc[i][j] = (floatx4){0.f, 0.f, 0.f, 0.f};

        const longx2* wp0 = (const longx2*)W2p
                          + ((size_t)(nh * 8 + wave * 2) * 64 + lane);
        const longx2* wp1 = wp0 + 64;
        // K-step stride = 16 pair-groups * 64 lanes = 1024 longx2

        longx2 fA0 = wp0[0],                  fA1 = wp1[0];
        longx2 fB0 = wp0[(size_t)1 * 1024],   fB1 = wp1[(size_t)1 * 1024];
        longx2 fC0, fC1, fD0, fD1;

        #pragma unroll 1
        for (int s = 0; s < 48; s += 4) {
            fC0 = wp0[(size_t)(s + 2) * 1024]; fC1 = wp1[(size_t)(s + 2) * 1024];
            C2_PHASE(fA0, fA1, s)
            fD0 = wp0[(size_t)(s + 3) * 1024]; fD1 = wp1[(size_t)(s + 3) * 1024];
            C2_PHASE(fB0, fB1, s + 1)
            fA0 = wp0[(size_t)(s + 4) * 1024]; fA1 = wp1[(size_t)(s + 4) * 1024]; // pads at 48/49
            C2_PHASE(fC0, fC1, s + 2)
            fB0 = wp0[(size_t)(s + 5) * 1024]; fB1 = wp1[(size_t)(s + 5) * 1024];
            C2_PHASE(fD0, fD1, s + 3)
        }

        if (nh == 0) {
            // half-A epilogue: gelu + fp16-pack into registers
            #pragma unroll
            for (int mt = 0; mt < 4; ++mt)
                #pragma unroll
                for (int nt = 0; nt < 4; ++nt) {
                    int col = wave * 64 + nt * 16 + m16;
                    float bsv = bias2[col];
                    float g0 = gelu_exact(acc[mt][nt][0] * INV2 + bsv);
                    float g1 = gelu_exact(acc[mt][nt][1] * INV2 + bsv);
                    float g2 = gelu_exact(acc[mt][nt][2] * INV2 + bsv);
                    float g3 = gelu_exact(acc[mt][nt][3] * INV2 + bsv);
                    aPk[mt][nt][0] = (half2v){(_Float16)g0, (_Float16)g1};
                    aPk[mt][nt][1] = (half2v){(_Float16)g2, (_Float16)g3};
                }
        } else {
            // half-B epilogue: gelu in place (stays in acc)
            #pragma unroll
            for (int mt = 0; mt < 4; ++mt)
                #pragma unroll
                for (int nt = 0; nt < 4; ++nt) {
                    int col = 256 + wave * 64 + nt * 16 + m16;
                    float bsv = bias2[col];
                    #pragma unroll
                    for (int r = 0; r < 4; ++r)
                        acc[mt][nt][r] = gelu_exact(acc[mt][nt][r] * INV2 + bsv);
                }
        }
    }
#undef C2_PHASE

    // LN row stats over full 512-col rows: half-A from aPk, half-B from acc
    #pragma unroll
    for (int mt = 0; mt < 4; ++mt) {
        #pragma unroll
        for (int r = 0; r < 4; ++r) {
            float rs = 0.f, rq = 0.f;
            #pragma unroll
            for (int nt = 0; nt < 4; ++nt) {
                float vA = (float)aPk[mt][nt][r >> 1][r & 1];
                float vB = acc[mt][nt][r];
                rs += vA + vB; rq += vA * vA + vB * vB;
            }
            rs += __shfl_xor(rs, 1);  rq += __shfl_xor(rq, 1);
            rs += __shfl_xor(rs, 2);  rq += __shfl_xor(rq, 2);
            rs += __shfl_xor(rs, 4);  rq += __shfl_xor(rq, 4);
            rs += __shfl_xor(rs, 8);  rq += __shfl_xor(rq, 8);
            if (m16 == 0) {
                int row = mt * 16 + q * 4 + r;
                part[row][wave][0] = rs;
                part[row][wave][1] = rq;
            }
        }
    }
    __syncthreads();
    if (tid < 128) {
        int row = tid >> 1, j = tid & 1;
        tot[row][j] = part[row][0][j] + part[row][1][j] + part[row][2][j] + part[row][3][j];
    }
    __syncthreads();

    float meanv[4][4], rstdv[4][4];
    #pragma unroll
    for (int mt = 0; mt < 4; ++mt)
        #pragma unroll
        for (int r = 0; r < 4; ++r) {
            int row = mt * 16 + q * 4 + r;
            float m = tot[row][0] * (1.0f / D_);
            float var = tot[row][1] * (1.0f / D_) - m * m;
            meanv[mt][r] = m;
            rstdv[mt][r] = rsqrtf((var > 0.0f ? var : 0.0f) + 1e-5f);
        }

    float csA[4], cqA[4], csB[4], cqB[4];
    float lgA[4], lbA[4], lgB[4], lbB[4];
    #pragma unroll
    for (int nt = 0; nt < 4; ++nt) {
        int colA = wave * 64 + nt * 16 + m16;
        lgA[nt] = ln_g[colA];       lbA[nt] = ln_b[colA];
        lgB[nt] = ln_g[colA + 256]; lbB[nt] = ln_b[colA + 256];
        csA[nt] = 0.f; cqA[nt] = 0.f; csB[nt] = 0.f; cqB[nt] = 0.f;
    }
    #pragma unroll
    for (int mt = 0; mt < 4; ++mt) {
        #pragma unroll
        for (int r = 0; r < 4; ++r) {
            int row = mt * 16 + q * 4 + r;
            float mk = mrow[row];
            float m = meanv[mt][r], rs = rstdv[mt][r];
            #pragma unroll
            for (int nt = 0; nt < 4; ++nt) {
                float vA = (float)aPk[mt][nt][r >> 1][r & 1];
                float vB = acc[mt][nt][r];
                float xnA = ((vA - m) * rs * lgA[nt] + lbA[nt]) * mk;
                float xnB = ((vB - m) * rs * lgB[nt] + lbB[nt]) * mk;
                csA[nt] += xnA; cqA[nt] += xnA * xnA;
                csB[nt] += xnB; cqB[nt] += xnB * xnB;
            }
        }
    }
    #pragma unroll
    for (int nt = 0; nt < 4; ++nt) {
        csA[nt] += __shfl_xor(csA[nt], 16);  cqA[nt] += __shfl_xor(cqA[nt], 16);
        csA[nt] += __shfl_xor(csA[nt], 32);  cqA[nt] += __shfl_xor(cqA[nt], 32);
        csB[nt] += __shfl_xor(csB[nt], 16);  cqB[nt] += __shfl_xor(cqB[nt], 16);
        csB[nt] += __shfl_xor(csB[nt], 32);  cqB[nt] += __shfl_xor(cqB[nt], 32);
    }
    if (lane < 16) {
        #pragma unroll
        for (int nt = 0; nt < 4; ++nt) {
            int colA = wave * 64 + nt * 16 + m16;
            colsum[colA][0] = csA[nt];       colsum[colA][1] = cqA[nt];
            colsum[colA + 256][0] = csB[nt]; colsum[colA + 256][1] = cqB[nt];
        }
    }
    __syncthreads();
    for (int i = tid; i < 512; i += 256) {
        atomicAdd(&psum[(size_t)b * D_ + i], colsum[i][0]);
        atomicAdd(&psumsq[(size_t)b * D_ + i], colsum[i][1]);
    }
}

// ---------------------------------------------------------------------------
// Kernels 4a/4b/4c: MLP head. k-split x2 parallelism (grid y 8, thread pairs
//   split the dot-product, __shfl_xor(1) combine) — kept from R3 (~+14 us).
// ---------------------------------------------------------------------------
__global__ __launch_bounds__(128) void mlp1_kernel(
    const float* __restrict__ psum, const float* __restrict__ psumsq,
    const float* __restrict__ sup_ws,
    const float* __restrict__ p1w, const float* __restrict__ p1b,
    float* __restrict__ s1_ws, float* __restrict__ nrm_ws)
{
    int b = blockIdx.x, jt = blockIdx.y;   // jt 0..7
    int tid = threadIdx.x;
    __shared__ float h[2 * D_];

    float n = sup_ws[b];
    float denom = (n > 1.0f) ? n : 1.0f;
    for (int i = tid; i < D_; i += 128) {
        float S = psum[(size_t)b * D_ + i];
        float Q = psumsq[(size_t)b * D_ + i];
        float mean = S / denom;
        float msum = Q - 2.0f * mean * S + n * mean * mean;
        float arg = msum / denom + 1e-6f;
        h[i] = mean;
        h[D_ + i] = sqrtf((arg > 0.0f) ? arg : 0.0f);
    }
    if (jt == 0 && tid == 0) nrm_ws[b] = 0.0f;
    __syncthreads();

    int d  = jt * 64 + (tid >> 1);
    int kh = tid & 1;
    float z = (kh == 0) ? p1b[d] : 0.0f;
    const float4* w4 = (const float4*)(p1w + (size_t)d * (2 * D_) + kh * D_);
    const float*  hh = &h[kh * D_];
    for (int jj = 0; jj < D_ / 4; ++jj) {
        float4 wv = w4[jj];
        z += hh[jj * 4 + 0] * wv.x + hh[jj * 4 + 1] * wv.y
           + hh[jj * 4 + 2] * wv.z + hh[jj * 4 + 3] * wv.w;
    }
    z += __shfl_xor(z, 1);
    if (kh == 0) s1_ws[(size_t)b * D_ + d] = gelu_exact(z);
}

__global__ __launch_bounds__(128) void mlp2_kernel(
    const float* __restrict__ s1_ws, const float* __restrict__ sup_ws,
    const float* __restrict__ p2w, const float* __restrict__ p2b,
    float* __restrict__ nrm_ws, float* __restrict__ out)
{
    int b = blockIdx.x, jt = blockIdx.y;   // jt 0..7
    int tid = threadIdx.x;
    __shared__ float s1[D_];
    __shared__ float red[128];

    for (int i = tid; i < D_; i += 128) s1[i] = s1_ws[(size_t)b * D_ + i];
    __syncthreads();

    int d  = jt * 64 + (tid >> 1);
    int kh = tid & 1;
    float z2 = (kh == 0) ? p2b[d] : 0.0f;
    const float4* w24 = (const float4*)(p2w + (size_t)d * D_ + kh * 256);
    const float*  ss  = &s1[kh * 256];
    for (int jj = 0; jj < 64; ++jj) {
        float4 wv = w24[jj];
        z2 += ss[jj * 4 + 0] * wv.x + ss[jj * 4 + 1] * wv.y
            + ss[jj * 4 + 2] * wv.z + ss[jj * 4 + 3] * wv.w;
    }
    z2 += __shfl_xor(z2, 1);
    float nsup = sup_ws[b];
    float st = tanhf(z2);
    if (!(nsup > 0.0f)) st = 0.0f;
    if (kh == 0) out[OFF1 + (size_t)b * D_ + d] = st;

    red[tid] = (kh == 0) ? st * st : 0.0f;
    __syncthreads();
    for (int s = 64; s > 0; s >>= 1) {
        if (tid < s) red[tid] += red[tid + s];
        __syncthreads();
    }
    if (tid == 0) atomicAdd(&nrm_ws[b], red[0]);
}

__global__ __launch_bounds__(64) void mlp3_kernel(
    const float* __restrict__ nrm_ws, float* __restrict__ out)
{
    int b = threadIdx.x;
    if (b < B_) out[OFF10 + b] = sqrtf(nrm_ws[b]);
}

// ---------------------------------------------------------------------------
extern "C" void kernel_launch(void* const* d_in, const int* in_sizes, int n_in,
                              void* d_out, int out_size, void* d_ws, size_t ws_size,
                              hipStream_t stream) {
    (void)in_sizes; (void)n_in; (void)out_size; (void)ws_size;
    const int*   unit_ids = (const int*)d_in[0];
    const float* dur      = (const float*)d_in[1];
    const float* mask     = (const float*)d_in[2];
    const float* emb      = (const float*)d_in[3];
    const float* aux_w    = (const float*)d_in[4];
    const float* aux_b    = (const float*)d_in[5];
    const float* conv1_w  = (const float*)d_in[6];
    const float* conv1_b  = (const float*)d_in[7];
    const float* conv2_w  = (const float*)d_in[8];
    const float* conv2_b  = (const float*)d_in[9];
    const float* ln_g     = (const float*)d_in[10];
    const float* ln_b     = (const float*)d_in[11];
    const float* p1_w     = (const float*)d_in[12];
    const float* p1_b     = (const float*)d_in[13];
    const float* p2_w     = (const float*)d_in[14];
    const float* p2_b     = (const float*)d_in[15];
    float* out = (float*)d_out;

    char* ws = (char*)d_ws;
    float*          rr     = (float*)(ws + WS_RR);
    float*          sup    = (float*)(ws + WS_SUP);
    float*          psum   = (float*)(ws + WS_PSUM);
    float*          psumsq = (float*)(ws + WS_PSUMSQ);
    unsigned char*  W1p    = (unsigned char*)(ws + WS_W1P);
    unsigned char*  W2p    = (unsigned char*)(ws + WS_W2P);
    unsigned char*  H1buf  = (unsigned char*)(ws + WS_H1);
    float*          s1_ws  = (float*)(ws + WS_S1);
    float*          nrm_ws = (float*)(ws + WS_NRM);

    init_kernel<<<dim3(64), dim3(256), 0, stream>>>(
        dur, mask, conv1_w, conv2_w, W1p, W2p, H1buf, rr, sup, psum, out);
    conv1g_kernel<<<dim3(32, 32), dim3(256), 0, stream>>>(
        unit_ids, rr, emb, aux_w, aux_b, W1p, conv1_b, H1buf);
    conv2ln_kernel<<<dim3(32, 32), dim3(256), 0, stream>>>(
        H1buf, W2p, conv2_b, ln_g, ln_b, mask, psum, psumsq);
    mlp1_kernel<<<dim3(32, 8), dim3(128), 0, stream>>>(
        psum, psumsq, sup, p1_w, p1_b, s1_ws, nrm_ws);
    mlp2_kernel<<<dim3(32, 8), dim3(128), 0, stream>>>(
        s1_ws, sup, p2_w, p2_b, nrm_ws, out);
    mlp3_kernel<<<dim3(1), dim3(64), 0, stream>>>(nrm_ws, out);
}

// Round 7
// 378.312 us; speedup vs baseline: 1.0000x; 1.0000x over previous
//
#include <hip/hip_runtime.h>
#include <hip/hip_bf16.h>
#include <math.h>

#define B_  32
#define T_  2048
#define D_  512
#define V_  1024
#define K_  3

typedef __attribute__((ext_vector_type(8))) short   short8;
typedef __attribute__((ext_vector_type(4))) float   floatx4;
typedef __attribute__((ext_vector_type(2))) long    longx2;   // 16 B paired fp8 frags

#define SCALE_H0 256.0f        // hidden0 fp8 scale (conv1 input)
#define SCALE_A  64.0f         // H1 activation fp8 scale (conv2 input)
#define SCALE_W  16.0f         // weight fp8 scale (both convs)
#define INV1 (1.0f/(SCALE_H0*SCALE_W))
#define INV2 (1.0f/(SCALE_A*SCALE_W))

// ---- output flat offsets (elements, fp32) ----
#define OFF0 0        // global_rate      [32]
#define OFF1 32       // summary_state    [32*512]
#define OFF2 16416    // residual_mean    [32]
#define OFF3 16448    // residual_var     [32]
#define OFF4 16480    // coverage         [32]
#define OFF5 16512    // mask             [32*2048]
#define OFF6 82048    // logdur           [32*2048]
#define OFF7 147584   // ref_residual     [32*2048]
#define OFF8 213120   // attn             [32*2048]
#define OFF9 278656   // prompt_role_fit  [32*2048]
#define OFF10 344192  // coeff_norm       [32]

// ---- workspace byte offsets (end 35,684,736 B < proven 36.34 MB) ----
// W1P/W2P are 48 K-steps * 16 KB + 2 PAD steps (32 KB) so conv1's
// branch-free depth-2 prefetch can over-read harmlessly.
#define WS_RR     0          // fp32 [32][2048]              262144 B
#define WS_SUP    262144     // fp32 [32]                       128 B
#define WS_PSUM   262272     // fp32 [32][512]                65536 B
#define WS_PSUMSQ 327808     // fp32 [32][512]                65536 B
#define WS_W1P    393344     // fp8 pair-packed conv1 w      819200 B (50 steps)
#define WS_W2P    1212544    // fp8 pair-packed conv2 w      819200 B (50 steps)
#define WS_H1     2031744    // fp8  [32][2050][512]       33587200 B
#define WS_S1     35618944   // fp32 [32][512] mlp hidden     65536 B
#define WS_NRM    35684480   // fp32 [32] coeff_norm accum      128 B
#define WS_CNT    35684608   // int  [32] mlp2 ticket           128 B

__device__ __forceinline__ float clampf(float v, float lo, float hi) {
    v = (v > lo) ? v : lo;
    return (v < hi) ? v : hi;
}
// NOTE: keep gelu_exact (erff) in the conv epilogues. The inlined tanh-form
// gelu_fast triggered accumulator spill-to-scratch in R8/R9/R10 (FETCH/WRITE
// blew up 10x, conv1g 130 -> 366 us). erff's call structure keeps acc
// register-resident. Do not "optimize" this again without checking WRITE_SIZE.
__device__ __forceinline__ float gelu_exact(float v) {
    return 0.5f * v * (1.0f + erff(v * 0.70710678118654752440f));
}
__device__ __forceinline__ unsigned char f2fp8(float x) {
    int v = __builtin_amdgcn_cvt_pk_fp8_f32(x, x, 0, false);
    return (unsigned char)(v & 0xFF);
}
__device__ __forceinline__ int pk4fp8(float a, float b, float c, float d) {
    int p0 = __builtin_amdgcn_cvt_pk_fp8_f32(a, b, 0, false);
    int p1 = __builtin_amdgcn_cvt_pk_fp8_f32(c, d, 0, false);
    return (p1 << 16) | (p0 & 0xFFFF);
}

__device__ __forceinline__ float block_reduce_sum(float v, float* red, int tid) {
    __syncthreads();
    red[tid] = v;
    __syncthreads();
    for (int s = 128; s > 0; s >>= 1) {
        if (tid < s) red[tid] += red[tid + s];
        __syncthreads();
    }
    float r = red[0];
    __syncthreads();
    return r;
}

// ---------------------------------------------------------------------------
// Kernel 1: MERGED init — blocks 0..31: per-batch stats (histogram-select
//   exact median + T-wise outputs); blocks 32..95: LDS-transpose weight
//   prepack (R7: one weight matrix per block, 2x the blocks — init was only
//   64 blocks on 256 CUs) + psum/H1-pad zeroing.
// Pair-packed weight layout: 16 B per (K-step s, pair-group pg, lane):
//   byte addr = ((s*16 + pg)*64 + lane)*16 + (ntg&1)*8, pg = ntg>>1.
// ---------------------------------------------------------------------------
#define NB 2048
#define HLO (-9.3f)
#define HSC ((float)NB / 10.05f)     // range [-9.3, 0.75]
#define WLS 1544                     // LDS row stride (1536 + 8 pad)
__global__ __launch_bounds__(256) void init_kernel(
    const float* __restrict__ dur, const float* __restrict__ maskp,
    const float* __restrict__ w1, const float* __restrict__ w2,
    unsigned char* __restrict__ W1p, unsigned char* __restrict__ W2p,
    unsigned char* __restrict__ H1buf,
    float* __restrict__ rr_ws, float* __restrict__ sup_ws,
    float* __restrict__ psum, float* __restrict__ out)
{
    int tid = threadIdx.x;

    if (blockIdx.x >= 32) {
        // ---------------- prepack part (LDS transpose) ----------------
        __shared__ unsigned char Wl[16 * WLS];       // 24704 B
        int pb  = blockIdx.x - 32;                   // 0..63
        int ws  = pb & 1;                            // 0 = w1, 1 = w2
        int ntg = pb >> 1;                           // 0..31 (16-col group)
        int lane = tid & 63, wave = tid >> 6;

        const float* wsrc = (ws ? w2 : w1) + (size_t)ntg * 16 * 1536;
        for (int i = tid; i < 6144; i += 256) {      // 16 cols x 1536 f
            float4 v = ((const float4*)wsrc)[i];
            int col_local = i / 384;                 // 384 float4 per col
            int pos = (i % 384) * 4;
            int word = pk4fp8(v.x * SCALE_W, v.y * SCALE_W,
                              v.z * SCALE_W, v.w * SCALE_W);
            *(int*)(&Wl[col_local * WLS + pos]) = word;
        }
        __syncthreads();

        int cl = lane & 15, qq = lane >> 4;
        int pg = ntg >> 1, half = ntg & 1;
        unsigned char* dst = ws ? W2p : W1p;
        for (int s = wave; s < 48; s += 4) {
            int ci = s & 15, k = s >> 4;
            const unsigned char* row = &Wl[cl * WLS];
            int kin = ci * 32 + qq * 8;
            unsigned char bb[8];
            #pragma unroll
            for (int e = 0; e < 8; ++e)
                bb[e] = row[(kin + e) * 3 + k];
            *(double*)(dst + (((size_t)(s * 16 + pg) * 64 + lane) * 16
                              + half * 8)) = *(double*)bb;
        }

        // zeroing: 64 blocks x 512 elems = 32768 elems each array
        #pragma unroll
        for (int j = 0; j < 2; ++j) {
            int idx = pb * 512 + j * 256 + tid;
            psum[idx] = 0.0f;                      // psum + psumsq contiguous
            int b = idx >> 10;
            int r = (idx >> 9) & 1;
            int d = idx & 511;
            H1buf[((size_t)b * 2050 + r) * 512 + d] = 0;
        }
        return;
    }

    // ---------------- stats part ----------------
    __shared__ int   hist[NB];
    __shared__ int   csum[256];
    __shared__ float red[256];
    __shared__ float cand[128];
    __shared__ float nsh, medsh;
    __shared__ int   sh_tb, sh_cb, sh_candn;

    int b = blockIdx.x;
    const float* durb = dur + (size_t)b * T_;
    const float* mkb  = maskp + (size_t)b * T_;

    float ld[8], mk[8];
    int   bn[8];
    float cnt = 0.0f;
    #pragma unroll
    for (int i = 0; i < 8; ++i) hist[tid * 8 + i] = 0;
    __syncthreads();
    #pragma unroll
    for (int i = 0; i < 8; ++i) {
        int t = tid + i * 256;
        float m = clampf(mkb[t], 0.0f, 1.0f);
        float dv = durb[t];
        dv = (dv >= 1e-4f) ? dv : 1e-4f;
        float l = logf(dv) * m;
        ld[i] = l; mk[i] = m;
        int bin = (int)((l - HLO) * HSC);
        bin = (bin < 0) ? 0 : ((bin > NB - 1) ? NB - 1 : bin);
        bn[i] = bin;
        if (m > 0.5f) { cnt += 1.0f; atomicAdd(&hist[bin], 1); }
    }
    float n = block_reduce_sum(cnt, red, tid);   // barriers make hist visible
    if (tid == 0) { nsh = n; sh_candn = 0; medsh = 0.0f; }

    // chunk sums + inclusive scan (Hillis-Steele)
    {
        int cs = 0;
        #pragma unroll
        for (int i = 0; i < 8; ++i) cs += hist[tid * 8 + i];
        csum[tid] = cs;
        __syncthreads();
        for (int off = 1; off < 256; off <<= 1) {
            int v = (tid >= off) ? csum[tid - off] : 0;
            __syncthreads();
            csum[tid] += v;
            __syncthreads();
        }
    }
    int ni = (int)(n + 0.5f);
    int k  = (ni > 0) ? ((ni - 1) >> 1) : 0;     // 0-indexed lower-median rank
    {
        int prevIncl = (tid > 0) ? csum[tid - 1] : 0;
        if (ni > 0 && k >= prevIncl && k < csum[tid]) {   // unique owner thread
            int cum = prevIncl, tb = tid * 8;
            #pragma unroll
            for (int i = 0; i < 8; ++i) {
                int c = hist[tid * 8 + i];
                if (k < cum + c) { tb = tid * 8 + i; break; }
                cum += c;
            }
            sh_tb = tb; sh_cb = cum;
        }
    }
    __syncthreads();
    // collect candidates in target bin
    if (ni > 0) {
        int tb = sh_tb;
        #pragma unroll
        for (int i = 0; i < 8; ++i) {
            if (mk[i] > 0.5f && bn[i] == tb) {
                int p = atomicAdd(&sh_candn, 1);
                if (p < 128) cand[p] = ld[i];
            }
        }
    }
    __syncthreads();
    if (tid == 0 && ni > 0) {
        int m = k - sh_cb;
        int cn = (sh_candn < 128) ? sh_candn : 128;
        float best = cand[0];
        for (int i = 0; i < cn; ++i) {
            int rank = 0;
            for (int j = 0; j < cn; ++j)
                rank += (cand[j] < cand[i]) || (cand[j] == cand[i] && j < i);
            if (rank == m) { best = cand[i]; break; }
        }
        medsh = best;
    }
    __syncthreads();
    float med = (ni > 0) ? medsh : 0.0f;
    med = clampf(med, -20.0f, 20.0f);

    float denom = (n > 1.0f) ? n : 1.0f;
    float rv[8];
    float ssum = 0.0f;
    #pragma unroll
    for (int i = 0; i < 8; ++i) { rv[i] = (ld[i] - med) * mk[i]; ssum += rv[i]; }
    float rsum = block_reduce_sum(ssum, red, tid);
    float rm = clampf(rsum / denom, -40.0f, 40.0f);

    float vsum_l = 0.0f;
    #pragma unroll
    for (int i = 0; i < 8; ++i) { float dd = rv[i] - rm; vsum_l += dd * dd * mk[i]; }
    float vsum = block_reduce_sum(vsum_l, red, tid);
    float var = clampf(vsum / denom, 1e-4f, 1e4f);

    float inv_sup = 1.0f / denom;
    #pragma unroll
    for (int i = 0; i < 8; ++i) {
        int t = tid + i * 256;
        size_t o = (size_t)b * T_ + t;
        out[OFF5 + o] = mk[i];
        out[OFF6 + o] = ld[i];
        out[OFF7 + o] = rv[i];
        out[OFF8 + o] = mk[i] * inv_sup;
        out[OFF9 + o] = rm * mk[i];
        rr_ws[o] = rv[i];
    }
    if (tid == 0) {
        out[OFF0 + b] = med;
        out[OFF2 + b] = rm;
        out[OFF3 + b] = var;
        float cov = n * (1.0f / (float)T_);
        out[OFF4 + b] = (cov > 0.05f) ? cov : 0.05f;
        sup_ws[b] = n;
    }
}

// ---------------------------------------------------------------------------
// Kernel 2: conv1 gather-GEMM, fp8 MFMA. BM=64 x 512 (two 256-col halves,
//   acc[4][4]). Pair-packed weights (one 16 B dwordx4 load covers two nt
//   fragments) + branch-free 4-phase register rotation, prefetch distance 2.
//   PROVEN R1: 195 -> ~58 us (~86% of the 50 us MFMA-issue floor).
//   launch_bounds MUST stay (256,3): (256,4) forces a 64-VGPR allocation
//   on this compiler (measured twice: R8, R12) -> accumulator spill ->
//   100+ MB scratch WRITE_SIZE, 2x slower. (256,3) = 76 VGPR, no scratch.
// ---------------------------------------------------------------------------
#define H0S 520
__global__ __launch_bounds__(256, 3) void conv1g_kernel(
    const int* __restrict__ ids, const float* __restrict__ rr,
    const float* __restrict__ emb,
    const float* __restrict__ aux_w, const float* __restrict__ aux_b,
    const unsigned char* __restrict__ W1p, const float* __restrict__ bias1,
    unsigned char* __restrict__ H1buf)
{
    __shared__ __align__(16) unsigned char H0s[66 * H0S];   // 34320 B
    __shared__ int   lid[66];
    __shared__ float lrr[66];

    int tile = blockIdx.x;          // 0..31
    int b    = blockIdx.y;          // 0..31
    int r0   = tile << 6;
    int tid  = threadIdx.x;
    int wave = tid >> 6, lane = tid & 63;
    int q = lane >> 4, m16 = lane & 15;

    if (tid < 66) {
        int t = r0 - 2 + tid;
        bool v = (t >= 0);
        lid[tid] = v ? ids[b * T_ + t] : -1;
        lrr[tid] = v ? rr[(size_t)b * T_ + t] : 0.0f;
    }
    __syncthreads();

    {   // gather hidden0 -> fp8 LDS
        int c4 = tid & 127;
        float4 aw = *(const float4*)(aux_w + c4 * 4);
        float4 ab = *(const float4*)(aux_b + c4 * 4);
        int rbase = tid >> 7;
        for (int j = 0; j < 33; ++j) {
            int row = rbase + j * 2;
            int id = lid[row];
            int word = 0;
            if (id >= 0) {
                float vr = lrr[row];
                float4 e = *(const float4*)(emb + (size_t)id * D_ + c4 * 4);
                word = pk4fp8((e.x + vr * aw.x + ab.x) * SCALE_H0,
                              (e.y + vr * aw.y + ab.y) * SCALE_H0,
                              (e.z + vr * aw.z + ab.z) * SCALE_H0,
                              (e.w + vr * aw.w + ab.w) * SCALE_H0);
            }
            *(int*)(&H0s[row * H0S + c4 * 4]) = word;
        }
    }
    __syncthreads();

    unsigned char* Ob = H1buf + ((size_t)b * 2050 + 2 + r0) * 512;

    // one K-step of MFMAs against a loaded weight pair (FR0 = nt{0,1}, FR1 = nt{2,3})
#define CONV1_PHASE(FR0, FR1, SS)                                              \
    {   int k1 = (SS) >> 4, ci = (SS) & 15;                                    \
        _Pragma("unroll")                                                      \
        for (int mt = 0; mt < 4; ++mt) {                                       \
            long afr = *(const long*)(&H0s[(mt * 16 + m16 + k1) * H0S + ci * 32 + q * 8]); \
            acc[mt][0] = __builtin_amdgcn_mfma_f32_16x16x32_fp8_fp8(afr, FR0[0], acc[mt][0], 0, 0, 0); \
            acc[mt][1] = __builtin_amdgcn_mfma_f32_16x16x32_fp8_fp8(afr, FR0[1], acc[mt][1], 0, 0, 0); \
            acc[mt][2] = __builtin_amdgcn_mfma_f32_16x16x32_fp8_fp8(afr, FR1[0], acc[mt][2], 0, 0, 0); \
            acc[mt][3] = __builtin_amdgcn_mfma_f32_16x16x32_fp8_fp8(afr, FR1[1], acc[mt][3], 0, 0, 0); \
        } }

    #pragma unroll
    for (int nh = 0; nh < 2; ++nh) {
        floatx4 acc[4][4];
        #pragma unroll
        for (int i = 0; i < 4; ++i)
            #pragma unroll
            for (int j = 0; j < 4; ++j)
                acc[i][j] = (floatx4){0.f, 0.f, 0.f, 0.f};

        // pair-group bases: pg0 covers nt{0,1}, pg0+1 covers nt{2,3}
        const longx2* wp0 = (const longx2*)W1p
                          + ((size_t)(0 * 16 + nh * 8 + wave * 2 + 0) * 64 + lane);
        const longx2* wp1 = wp0 + 64;
        // K-step stride = 16 pair-groups * 64 lanes = 1024 longx2

        longx2 fA0 = wp0[0],                  fA1 = wp1[0];
        longx2 fB0 = wp0[(size_t)1 * 1024],   fB1 = wp1[(size_t)1 * 1024];
        longx2 fC0, fC1, fD0, fD1;

        #pragma unroll 1
        for (int s = 0; s < 48; s += 4) {
            fC0 = wp0[(size_t)(s + 2) * 1024]; fC1 = wp1[(size_t)(s + 2) * 1024];
            CONV1_PHASE(fA0, fA1, s)
            fD0 = wp0[(size_t)(s + 3) * 1024]; fD1 = wp1[(size_t)(s + 3) * 1024];
            CONV1_PHASE(fB0, fB1, s + 1)
            fA0 = wp0[(size_t)(s + 4) * 1024]; fA1 = wp1[(size_t)(s + 4) * 1024]; // pads at 48/49
            CONV1_PHASE(fC0, fC1, s + 2)
            fB0 = wp0[(size_t)(s + 5) * 1024]; fB1 = wp1[(size_t)(s + 5) * 1024];
            CONV1_PHASE(fD0, fD1, s + 3)
        }

        #pragma unroll
        for (int mt = 0; mt < 4; ++mt) {
            #pragma unroll
            for (int nt = 0; nt < 4; ++nt) {
                int col = nh * 256 + wave * 64 + nt * 16 + m16;
                float bsv = bias1[col];
                #pragma unroll
                for (int r = 0; r < 4; ++r) {
                    int row = mt * 16 + q * 4 + r;
                    float v = gelu_exact(acc[mt][nt][r] * INV1 + bsv) * SCALE_A;
                    Ob[(size_t)row * 512 + col] = f2fp8(v);
                }
            }
        }
    }
#undef CONV1_PHASE
}

// ---------------------------------------------------------------------------
// Kernel 3: conv2 (fp8 MFMA) + gelu + LN + masked column sums.
//   R7: K-loop restructuring ABANDONED after 5 falsifications (R2 null,
//   R3 regress, R4 spill, R5 null, R6 spill) — conv2's LN epilogue leaves
//   no register slack; added live state spills or gets sunk. New lever:
//   OCCUPANCY. R5 ran VGPR 116 + AGPR 64 = 180/thread -> 2 waves/SIMD (22%).
//   launch_bounds (256,3) caps total at ~170 -> VGPR <= ~106 -> 3 waves/SIMD
//   (conv1 runs 3 waves at 140 total and hits 86%-of-floor). To help the
//   allocator shave ~12 regs: single weight base pointer + compile-time
//   offsets 0/1024/2048/3072 B (fold into global_load imm field, ~6 VGPR).
//   TRIPWIRE: WRITE_SIZE >> 8 MB (squeeze spilled) or dur > 137 us =>
//   revert launch_bounds to (256,2).
// ---------------------------------------------------------------------------
#define H1S 520
__global__ __launch_bounds__(256, 3) void conv2ln_kernel(
    const unsigned char* __restrict__ H1buf, const unsigned char* __restrict__ W2p,
    const float* __restrict__ bias2,
    const float* __restrict__ ln_g, const float* __restrict__ ln_b,
    const float* __restrict__ maskp,
    float* __restrict__ psum, float* __restrict__ psumsq)
{
    __shared__ __align__(16) unsigned char H1s[34 * H1S];   // 17680 B
    __shared__ float mrow[32];
    __shared__ float part[32][4][2];
    __shared__ float tot[32][2];
    __shared__ float colsum[512][2];

    int tile = blockIdx.x;          // 0..63
    int b    = blockIdx.y;          // 0..31
    int r0   = tile << 5;           // output rows r0..r0+31
    int tid  = threadIdx.x;
    int wave = tid >> 6, lane = tid & 63;
    int q = lane >> 4, m16 = lane & 15;
    int nbase = wave << 7;

    const unsigned char* src = H1buf + ((size_t)b * 2050 + r0) * 512;
    for (int g = tid; g < 34 * 32; g += 256) {
        int row = g >> 5, h = g & 31;
        *(float4*)(&H1s[row * H1S + h * 16]) = *(const float4*)(src + (size_t)row * 512 + h * 16);
    }
    if (tid < 32)
        mrow[tid] = clampf(maskp[(size_t)b * T_ + r0 + tid], 0.0f, 1.0f);
    __syncthreads();

    floatx4 acc[2][8];
    #pragma unroll
    for (int i = 0; i < 2; ++i)
        #pragma unroll
        for (int j = 0; j < 8; ++j)
            acc[i][j] = (floatx4){0.f, 0.f, 0.f, 0.f};

    // single weight stream base: pair-groups wave*4 .. wave*4+3 are at
    // compile-time byte offsets 0 / 1024 / 2048 / 3072 from wq (imm-foldable)
    const longx2* wq = (const longx2*)W2p + ((size_t)(wave * 4) * 64 + lane);
    // K-step stride = 16 pair-groups * 64 lanes = 1024 longx2

    #pragma unroll 2
    for (int s = 0; s < 48; ++s) {
        int k2 = s >> 4, ci = s & 15;
        longx2 f0 = wq[(size_t)s * 1024];
        longx2 f1 = wq[(size_t)s * 1024 + 64];
        longx2 f2 = wq[(size_t)s * 1024 + 128];
        longx2 f3 = wq[(size_t)s * 1024 + 192];
        #pragma unroll
        for (int mt = 0; mt < 2; ++mt) {
            long afr = *(const long*)(&H1s[(mt * 16 + m16 + k2) * H1S + ci * 32 + q * 8]);
            acc[mt][0] = __builtin_amdgcn_mfma_f32_16x16x32_fp8_fp8(afr, f0[0], acc[mt][0], 0, 0, 0);
            acc[mt][1] = __builtin_amdgcn_mfma_f32_16x16x32_fp8_fp8(afr, f0[1], acc[mt][1], 0, 0, 0);
            acc[mt][2] = __builtin_amdgcn_mfma_f32_16x16x32_fp8_fp8(afr, f1[0], acc[mt][2], 0, 0, 0);
            acc[mt][3] = __builtin_amdgcn_mfma_f32_16x16x32_fp8_fp8(afr, f1[1], acc[mt][3], 0, 0, 0);
            acc[mt][4] = __builtin_amdgcn_mfma_f32_16x16x32_fp8_fp8(afr, f2[0], acc[mt][4], 0, 0, 0);
            acc[mt][5] = __builtin_amdgcn_mfma_f32_16x16x32_fp8_fp8(afr, f2[1], acc[mt][5], 0, 0, 0);
            acc[mt][6] = __builtin_amdgcn_mfma_f32_16x16x32_fp8_fp8(afr, f3[0], acc[mt][6], 0, 0, 0);
            acc[mt][7] = __builtin_amdgcn_mfma_f32_16x16x32_fp8_fp8(afr, f3[1], acc[mt][7], 0, 0, 0);
        }
    }

    // epilogue: descale + bias + gelu
    #pragma unroll
    for (int mt = 0; mt < 2; ++mt)
        #pragma unroll
        for (int nt = 0; nt < 8; ++nt) {
            int col = nbase + nt * 16 + m16;
            float bsv = bias2[col];
            #pragma unroll
            for (int r = 0; r < 4; ++r)
                acc[mt][nt][r] = gelu_exact(acc[mt][nt][r] * INV2 + bsv);
        }

    // LN row stats
    #pragma unroll
    for (int mt = 0; mt < 2; ++mt) {
        #pragma unroll
        for (int r = 0; r < 4; ++r) {
            float rs = 0.f, rq = 0.f;
            #pragma unroll
            for (int nt = 0; nt < 8; ++nt) {
                float v = acc[mt][nt][r];
                rs += v; rq += v * v;
            }
            rs += __shfl_xor(rs, 1);  rq += __shfl_xor(rq, 1);
            rs += __shfl_xor(rs, 2);  rq += __shfl_xor(rq, 2);
            rs += __shfl_xor(rs, 4);  rq += __shfl_xor(rq, 4);
            rs += __shfl_xor(rs, 8);  rq += __shfl_xor(rq, 8);
            if (m16 == 0) {
                int row = mt * 16 + q * 4 + r;
                part[row][wave][0] = rs;
                part[row][wave][1] = rq;
            }
        }
    }
    __syncthreads();
    if (tid < 64) {
        int row = tid >> 1, j = tid & 1;
        tot[row][j] = part[row][0][j] + part[row][1][j] + part[row][2][j] + part[row][3][j];
    }
    __syncthreads();

    float meanv[2][4], rstdv[2][4];
    #pragma unroll
    for (int mt = 0; mt < 2; ++mt)
        #pragma unroll
        for (int r = 0; r < 4; ++r) {
            int row = mt * 16 + q * 4 + r;
            float m = tot[row][0] * (1.0f / D_);
            float var = tot[row][1] * (1.0f / D_) - m * m;
            meanv[mt][r] = m;
            rstdv[mt][r] = rsqrtf((var > 0.0f ? var : 0.0f) + 1e-5f);
        }

    float cs[8], cq[8];
    #pragma unroll
    for (int nt = 0; nt < 8; ++nt) { cs[nt] = 0.f; cq[nt] = 0.f; }
    #pragma unroll
    for (int mt = 0; mt < 2; ++mt) {
        #pragma unroll
        for (int r = 0; r < 4; ++r) {
            int row = mt * 16 + q * 4 + r;
            float mk = mrow[row];
            float m = meanv[mt][r], rs = rstdv[mt][r];
            #pragma unroll
            for (int nt = 0; nt < 8; ++nt) {
                int col = nbase + nt * 16 + m16;
                float xn = ((acc[mt][nt][r] - m) * rs * ln_g[col] + ln_b[col]) * mk;
                cs[nt] += xn;
                cq[nt] += xn * xn;
            }
        }
    }
    #pragma unroll
    for (int nt = 0; nt < 8; ++nt) {
        cs[nt] += __shfl_xor(cs[nt], 16);  cq[nt] += __shfl_xor(cq[nt], 16);
        cs[nt] += __shfl_xor(cs[nt], 32);  cq[nt] += __shfl_xor(cq[nt], 32);
    }
    if (lane < 16) {
        #pragma unroll
        for (int nt = 0; nt < 8; ++nt) {
            int col = nbase + nt * 16 + m16;
            colsum[col][0] = cs[nt];
            colsum[col][1] = cq[nt];
        }
    }
    __syncthreads();
    for (int i = tid; i < 512; i += 256) {
        atomicAdd(&psum[(size_t)b * D_ + i], colsum[i][0]);
        atomicAdd(&psumsq[(size_t)b * D_ + i], colsum[i][1]);
    }
}

// ---------------------------------------------------------------------------
// Kernels 4a/4b: MLP head. k-split x2 parallelism (grid y 8, thread pairs
//   split the dot-product, __shfl_xor(1) combine) — kept from R3 (~+14 us).
//   R7: mlp3 launch eliminated — last-finishing mlp2 block per batch writes
//   coeff_norm via device-scope ticket counter (cnt_ws, re-zeroed in mlp1).
// ---------------------------------------------------------------------------
__global__ __launch_bounds__(128) void mlp1_kernel(
    const float* __restrict__ psum, const float* __restrict__ psumsq,
    const float* __restrict__ sup_ws,
    const float* __restrict__ p1w, const float* __restrict__ p1b,
    float* __restrict__ s1_ws, float* __restrict__ nrm_ws,
    int* __restrict__ cnt_ws)
{
    int b = blockIdx.x, jt = blockIdx.y;   // jt 0..7
    int tid = threadIdx.x;
    __shared__ float h[2 * D_];

    float n = sup_ws[b];
    float denom = (n > 1.0f) ? n : 1.0f;
    for (int i = tid; i < D_; i += 128) {
        float S = psum[(size_t)b * D_ + i];
        float Q = psumsq[(size_t)b * D_ + i];
        float mean = S / denom;
        float msum = Q - 2.0f * mean * S + n * mean * mean;
        float arg = msum / denom + 1e-6f;
        h[i] = mean;
        h[D_ + i] = sqrtf((arg > 0.0f) ? arg : 0.0f);
    }
    if (jt == 0 && tid == 0) { nrm_ws[b] = 0.0f; cnt_ws[b] = 0; }
    __syncthreads();

    int d  = jt * 64 + (tid >> 1);
    int kh = tid & 1;
    float z = (kh == 0) ? p1b[d] : 0.0f;
    const float4* w4 = (const float4*)(p1w + (size_t)d * (2 * D_) + kh * D_);
    const float*  hh = &h[kh * D_];
    for (int jj = 0; jj < D_ / 4; ++jj) {
        float4 wv = w4[jj];
        z += hh[jj * 4 + 0] * wv.x + hh[jj * 4 + 1] * wv.y
           + hh[jj * 4 + 2] * wv.z + hh[jj * 4 + 3] * wv.w;
    }
    z += __shfl_xor(z, 1);
    if (kh == 0) s1_ws[(size_t)b * D_ + d] = gelu_exact(z);
}

__global__ __launch_bounds__(128) void mlp2_kernel(
    const float* __restrict__ s1_ws, const float* __restrict__ sup_ws,
    const float* __restrict__ p2w, const float* __restrict__ p2b,
    float* __restrict__ nrm_ws, int* __restrict__ cnt_ws,
    float* __restrict__ out)
{
    int b = blockIdx.x, jt = blockIdx.y;   // jt 0..7
    int tid = threadIdx.x;
    __shared__ float s1[D_];
    __shared__ float red[128];

    for (int i = tid; i < D_; i += 128) s1[i] = s1_ws[(size_t)b * D_ + i];
    __syncthreads();

    int d  = jt * 64 + (tid >> 1);
    int kh = tid & 1;
    float z2 = (kh == 0) ? p2b[d] : 0.0f;
    const float4* w24 = (const float4*)(p2w + (size_t)d * D_ + kh * 256);
    const float*  ss  = &s1[kh * 256];
    for (int jj = 0; jj < 64; ++jj) {
        float4 wv = w24[jj];
        z2 += ss[jj * 4 + 0] * wv.x + ss[jj * 4 + 1] * wv.y
            + ss[jj * 4 + 2] * wv.z + ss[jj * 4 + 3] * wv.w;
    }
    z2 += __shfl_xor(z2, 1);
    float nsup = sup_ws[b];
    float st = tanhf(z2);
    if (!(nsup > 0.0f)) st = 0.0f;
    if (kh == 0) out[OFF1 + (size_t)b * D_ + d] = st;

    red[tid] = (kh == 0) ? st * st : 0.0f;
    __syncthreads();
    for (int s = 64; s > 0; s >>= 1) {
        if (tid < s) red[tid] += red[tid + s];
        __syncthreads();
    }
    if (tid == 0) {
        atomicAdd(&nrm_ws[b], red[0]);
        __threadfence();
        int old = atomicAdd(&cnt_ws[b], 1);
        if (old == 7) {
            float nv = atomicAdd(&nrm_ws[b], 0.0f);   // coherent read
            out[OFF10 + b] = sqrtf(nv);
        }
    }
}

// ---------------------------------------------------------------------------
extern "C" void kernel_launch(void* const* d_in, const int* in_sizes, int n_in,
                              void* d_out, int out_size, void* d_ws, size_t ws_size,
                              hipStream_t stream) {
    (void)in_sizes; (void)n_in; (void)out_size; (void)ws_size;
    const int*   unit_ids = (const int*)d_in[0];
    const float* dur      = (const float*)d_in[1];
    const float* mask     = (const float*)d_in[2];
    const float* emb      = (const float*)d_in[3];
    const float* aux_w    = (const float*)d_in[4];
    const float* aux_b    = (const float*)d_in[5];
    const float* conv1_w  = (const float*)d_in[6];
    const float* conv1_b  = (const float*)d_in[7];
    const float* conv2_w  = (const float*)d_in[8];
    const float* conv2_b  = (const float*)d_in[9];
    const float* ln_g     = (const float*)d_in[10];
    const float* ln_b     = (const float*)d_in[11];
    const float* p1_w     = (const float*)d_in[12];
    const float* p1_b     = (const float*)d_in[13];
    const float* p2_w     = (const float*)d_in[14];
    const float* p2_b     = (const float*)d_in[15];
    float* out = (float*)d_out;

    char* ws = (char*)d_ws;
    float*          rr     = (float*)(ws + WS_RR);
    float*          sup    = (float*)(ws + WS_SUP);
    float*          psum   = (float*)(ws + WS_PSUM);
    float*          psumsq = (float*)(ws + WS_PSUMSQ);
    unsigned char*  W1p    = (unsigned char*)(ws + WS_W1P);
    unsigned char*  W2p    = (unsigned char*)(ws + WS_W2P);
    unsigned char*  H1buf  = (unsigned char*)(ws + WS_H1);
    float*          s1_ws  = (float*)(ws + WS_S1);
    float*          nrm_ws = (float*)(ws + WS_NRM);
    int*            cnt_ws = (int*)(ws + WS_CNT);

    init_kernel<<<dim3(96), dim3(256), 0, stream>>>(
        dur, mask, conv1_w, conv2_w, W1p, W2p, H1buf, rr, sup, psum, out);
    conv1g_kernel<<<dim3(32, 32), dim3(256), 0, stream>>>(
        unit_ids, rr, emb, aux_w, aux_b, W1p, conv1_b, H1buf);
    conv2ln_kernel<<<dim3(64, 32), dim3(256), 0, stream>>>(
        H1buf, W2p, conv2_b, ln_g, ln_b, mask, psum, psumsq);
    mlp1_kernel<<<dim3(32, 8), dim3(128), 0, stream>>>(
        psum, psumsq, sup, p1_w, p1_b, s1_ws, nrm_ws, cnt_ws);
    mlp2_kernel<<<dim3(32, 8), dim3(128), 0, stream>>>(
        s1_ws, sup, p2_w, p2_b, nrm_ws, cnt_ws, out);
}

// Round 8
// 307.291 us; speedup vs baseline: 1.2312x; 1.2311x over previous
//
#include <hip/hip_runtime.h>
#include <hip/hip_bf16.h>
#include <math.h>

#define B_  32
#define T_  2048
#define D_  512
#define V_  1024
#define K_  3

typedef __attribute__((ext_vector_type(8))) short    short8;
typedef __attribute__((ext_vector_type(4))) float    floatx4;
typedef __attribute__((ext_vector_type(2))) long     longx2;   // 16 B paired fp8 frags

#define SCALE_H0 256.0f        // hidden0 fp8 scale (conv1 input)
#define SCALE_A  64.0f         // H1 activation fp8 scale (conv2 input)
#define SCALE_W  16.0f         // weight fp8 scale (both convs)
#define INV1 (1.0f/(SCALE_H0*SCALE_W))
#define INV2 (1.0f/(SCALE_A*SCALE_W))

// ---- output flat offsets (elements, fp32) ----
#define OFF0 0        // global_rate      [32]
#define OFF1 32       // summary_state    [32*512]
#define OFF2 16416    // residual_mean    [32]
#define OFF3 16448    // residual_var     [32]
#define OFF4 16480    // coverage         [32]
#define OFF5 16512    // mask             [32*2048]
#define OFF6 82048    // logdur           [32*2048]
#define OFF7 147584   // ref_residual     [32*2048]
#define OFF8 213120   // attn             [32*2048]
#define OFF9 278656   // prompt_role_fit  [32*2048]
#define OFF10 344192  // coeff_norm       [32]

// ---- workspace byte offsets (end 35,684,736 B < proven 36.34 MB) ----
// W1P/W2P are 48 K-steps * 16 KB + 2 PAD steps (32 KB) so the convs'
// branch-free depth-2 prefetch can over-read harmlessly.
#define WS_RR     0          // fp32 [32][2048]              262144 B
#define WS_SUP    262144     // fp32 [32]                       128 B
#define WS_PSUM   262272     // fp32 [32][512]                65536 B
#define WS_PSUMSQ 327808     // fp32 [32][512]                65536 B
#define WS_W1P    393344     // fp8 pair-packed conv1 w      819200 B (50 steps)
#define WS_W2P    1212544    // fp8 pair-packed conv2 w      819200 B (50 steps)
#define WS_H1     2031744    // fp8  [32][2050][512]       33587200 B
#define WS_S1     35618944   // fp32 [32][512] mlp hidden     65536 B
#define WS_NRM    35684480   // fp32 [32] coeff_norm accum      128 B
#define WS_CNT    35684608   // int  [32] mlp2 ticket           128 B

__device__ __forceinline__ float clampf(float v, float lo, float hi) {
    v = (v > lo) ? v : lo;
    return (v < hi) ? v : hi;
}
// NOTE: keep gelu_exact (erff) in the conv epilogues. The inlined tanh-form
// gelu_fast triggered accumulator spill-to-scratch in R8/R9/R10 (FETCH/WRITE
// blew up 10x, conv1g 130 -> 366 us). erff's call structure keeps acc
// register-resident. Do not "optimize" this again without checking WRITE_SIZE.
__device__ __forceinline__ float gelu_exact(float v) {
    return 0.5f * v * (1.0f + erff(v * 0.70710678118654752440f));
}
__device__ __forceinline__ unsigned char f2fp8(float x) {
    int v = __builtin_amdgcn_cvt_pk_fp8_f32(x, x, 0, false);
    return (unsigned char)(v & 0xFF);
}
__device__ __forceinline__ int pk4fp8(float a, float b, float c, float d) {
    int p0 = __builtin_amdgcn_cvt_pk_fp8_f32(a, b, 0, false);
    int p1 = __builtin_amdgcn_cvt_pk_fp8_f32(c, d, 0, false);
    return (p1 << 16) | (p0 & 0xFFFF);
}

__device__ __forceinline__ float block_reduce_sum(float v, float* red, int tid) {
    __syncthreads();
    red[tid] = v;
    __syncthreads();
    for (int s = 128; s > 0; s >>= 1) {
        if (tid < s) red[tid] += red[tid + s];
        __syncthreads();
    }
    float r = red[0];
    __syncthreads();
    return r;
}

// ---------------------------------------------------------------------------
// Kernel 1: MERGED init — blocks 0..31: per-batch stats (histogram-select
//   exact median + T-wise outputs); blocks 32..95: LDS-transpose weight
//   prepack (one weight matrix per block) + psum/H1-pad zeroing.
// Pair-packed weight layout: 16 B per (K-step s, pair-group pg, lane):
//   byte addr = ((s*16 + pg)*64 + lane)*16 + (ntg&1)*8, pg = ntg>>1.
// ---------------------------------------------------------------------------
#define NB 2048
#define HLO (-9.3f)
#define HSC ((float)NB / 10.05f)     // range [-9.3, 0.75]
#define WLS 1544                     // LDS row stride (1536 + 8 pad)
__global__ __launch_bounds__(256) void init_kernel(
    const float* __restrict__ dur, const float* __restrict__ maskp,
    const float* __restrict__ w1, const float* __restrict__ w2,
    unsigned char* __restrict__ W1p, unsigned char* __restrict__ W2p,
    unsigned char* __restrict__ H1buf,
    float* __restrict__ rr_ws, float* __restrict__ sup_ws,
    float* __restrict__ psum, float* __restrict__ out)
{
    int tid = threadIdx.x;

    if (blockIdx.x >= 32) {
        // ---------------- prepack part (LDS transpose) ----------------
        __shared__ unsigned char Wl[16 * WLS];       // 24704 B
        int pb  = blockIdx.x - 32;                   // 0..63
        int ws  = pb & 1;                            // 0 = w1, 1 = w2
        int ntg = pb >> 1;                           // 0..31 (16-col group)
        int lane = tid & 63, wave = tid >> 6;

        const float* wsrc = (ws ? w2 : w1) + (size_t)ntg * 16 * 1536;
        for (int i = tid; i < 6144; i += 256) {      // 16 cols x 1536 f
            float4 v = ((const float4*)wsrc)[i];
            int col_local = i / 384;                 // 384 float4 per col
            int pos = (i % 384) * 4;
            int word = pk4fp8(v.x * SCALE_W, v.y * SCALE_W,
                              v.z * SCALE_W, v.w * SCALE_W);
            *(int*)(&Wl[col_local * WLS + pos]) = word;
        }
        __syncthreads();

        int cl = lane & 15, qq = lane >> 4;
        int pg = ntg >> 1, half = ntg & 1;
        unsigned char* dst = ws ? W2p : W1p;
        for (int s = wave; s < 48; s += 4) {
            int ci = s & 15, k = s >> 4;
            const unsigned char* row = &Wl[cl * WLS];
            int kin = ci * 32 + qq * 8;
            unsigned char bb[8];
            #pragma unroll
            for (int e = 0; e < 8; ++e)
                bb[e] = row[(kin + e) * 3 + k];
            *(double*)(dst + (((size_t)(s * 16 + pg) * 64 + lane) * 16
                              + half * 8)) = *(double*)bb;
        }

        // zeroing: 64 blocks x 512 elems = 32768 elems each array
        #pragma unroll
        for (int j = 0; j < 2; ++j) {
            int idx = pb * 512 + j * 256 + tid;
            psum[idx] = 0.0f;                      // psum + psumsq contiguous
            int b = idx >> 10;
            int r = (idx >> 9) & 1;
            int d = idx & 511;
            H1buf[((size_t)b * 2050 + r) * 512 + d] = 0;
        }
        return;
    }

    // ---------------- stats part ----------------
    __shared__ int   hist[NB];
    __shared__ int   csum[256];
    __shared__ float red[256];
    __shared__ float cand[128];
    __shared__ float nsh, medsh;
    __shared__ int   sh_tb, sh_cb, sh_candn;

    int b = blockIdx.x;
    const float* durb = dur + (size_t)b * T_;
    const float* mkb  = maskp + (size_t)b * T_;

    float ld[8], mk[8];
    int   bn[8];
    float cnt = 0.0f;
    #pragma unroll
    for (int i = 0; i < 8; ++i) hist[tid * 8 + i] = 0;
    __syncthreads();
    #pragma unroll
    for (int i = 0; i < 8; ++i) {
        int t = tid + i * 256;
        float m = clampf(mkb[t], 0.0f, 1.0f);
        float dv = durb[t];
        dv = (dv >= 1e-4f) ? dv : 1e-4f;
        float l = logf(dv) * m;
        ld[i] = l; mk[i] = m;
        int bin = (int)((l - HLO) * HSC);
        bin = (bin < 0) ? 0 : ((bin > NB - 1) ? NB - 1 : bin);
        bn[i] = bin;
        if (m > 0.5f) { cnt += 1.0f; atomicAdd(&hist[bin], 1); }
    }
    float n = block_reduce_sum(cnt, red, tid);   // barriers make hist visible
    if (tid == 0) { nsh = n; sh_candn = 0; medsh = 0.0f; }

    // chunk sums + inclusive scan (Hillis-Steele)
    {
        int cs = 0;
        #pragma unroll
        for (int i = 0; i < 8; ++i) cs += hist[tid * 8 + i];
        csum[tid] = cs;
        __syncthreads();
        for (int off = 1; off < 256; off <<= 1) {
            int v = (tid >= off) ? csum[tid - off] : 0;
            __syncthreads();
            csum[tid] += v;
            __syncthreads();
        }
    }
    int ni = (int)(n + 0.5f);
    int k  = (ni > 0) ? ((ni - 1) >> 1) : 0;     // 0-indexed lower-median rank
    {
        int prevIncl = (tid > 0) ? csum[tid - 1] : 0;
        if (ni > 0 && k >= prevIncl && k < csum[tid]) {   // unique owner thread
            int cum = prevIncl, tb = tid * 8;
            #pragma unroll
            for (int i = 0; i < 8; ++i) {
                int c = hist[tid * 8 + i];
                if (k < cum + c) { tb = tid * 8 + i; break; }
                cum += c;
            }
            sh_tb = tb; sh_cb = cum;
        }
    }
    __syncthreads();
    // collect candidates in target bin
    if (ni > 0) {
        int tb = sh_tb;
        #pragma unroll
        for (int i = 0; i < 8; ++i) {
            if (mk[i] > 0.5f && bn[i] == tb) {
                int p = atomicAdd(&sh_candn, 1);
                if (p < 128) cand[p] = ld[i];
            }
        }
    }
    __syncthreads();
    if (tid == 0 && ni > 0) {
        int m = k - sh_cb;
        int cn = (sh_candn < 128) ? sh_candn : 128;
        float best = cand[0];
        for (int i = 0; i < cn; ++i) {
            int rank = 0;
            for (int j = 0; j < cn; ++j)
                rank += (cand[j] < cand[i]) || (cand[j] == cand[i] && j < i);
            if (rank == m) { best = cand[i]; break; }
        }
        medsh = best;
    }
    __syncthreads();
    float med = (ni > 0) ? medsh : 0.0f;
    med = clampf(med, -20.0f, 20.0f);

    float denom = (n > 1.0f) ? n : 1.0f;
    float rv[8];
    float ssum = 0.0f;
    #pragma unroll
    for (int i = 0; i < 8; ++i) { rv[i] = (ld[i] - med) * mk[i]; ssum += rv[i]; }
    float rsum = block_reduce_sum(ssum, red, tid);
    float rm = clampf(rsum / denom, -40.0f, 40.0f);

    float vsum_l = 0.0f;
    #pragma unroll
    for (int i = 0; i < 8; ++i) { float dd = rv[i] - rm; vsum_l += dd * dd * mk[i]; }
    float vsum = block_reduce_sum(vsum_l, red, tid);
    float var = clampf(vsum / denom, 1e-4f, 1e4f);

    float inv_sup = 1.0f / denom;
    #pragma unroll
    for (int i = 0; i < 8; ++i) {
        int t = tid + i * 256;
        size_t o = (size_t)b * T_ + t;
        out[OFF5 + o] = mk[i];
        out[OFF6 + o] = ld[i];
        out[OFF7 + o] = rv[i];
        out[OFF8 + o] = mk[i] * inv_sup;
        out[OFF9 + o] = rm * mk[i];
        rr_ws[o] = rv[i];
    }
    if (tid == 0) {
        out[OFF0 + b] = med;
        out[OFF2 + b] = rm;
        out[OFF3 + b] = var;
        float cov = n * (1.0f / (float)T_);
        out[OFF4 + b] = (cov > 0.05f) ? cov : 0.05f;
        sup_ws[b] = n;
    }
}

// ---------------------------------------------------------------------------
// Kernel 2: conv1 gather-GEMM, fp8 MFMA. BM=64 x 512 (two 256-col halves,
//   acc[4][4]). Pair-packed weights (one 16 B dwordx4 load covers two nt
//   fragments) + branch-free 4-phase register rotation, prefetch distance 2.
//   PROVEN R1: 195 -> ~58 us (~86% of the 50 us MFMA-issue floor).
//   launch_bounds MUST stay (256,3): (256,4) forces a 64-VGPR allocation
//   on this compiler (measured twice: R8, R12) -> accumulator spill ->
//   100+ MB scratch WRITE_SIZE, 2x slower. (256,3) = 76 VGPR, no scratch.
// ---------------------------------------------------------------------------
#define H0S 520
__global__ __launch_bounds__(256, 3) void conv1g_kernel(
    const int* __restrict__ ids, const float* __restrict__ rr,
    const float* __restrict__ emb,
    const float* __restrict__ aux_w, const float* __restrict__ aux_b,
    const unsigned char* __restrict__ W1p, const float* __restrict__ bias1,
    unsigned char* __restrict__ H1buf)
{
    __shared__ __align__(16) unsigned char H0s[66 * H0S];   // 34320 B
    __shared__ int   lid[66];
    __shared__ float lrr[66];

    int tile = blockIdx.x;          // 0..31
    int b    = blockIdx.y;          // 0..31
    int r0   = tile << 6;
    int tid  = threadIdx.x;
    int wave = tid >> 6, lane = tid & 63;
    int q = lane >> 4, m16 = lane & 15;

    if (tid < 66) {
        int t = r0 - 2 + tid;
        bool v = (t >= 0);
        lid[tid] = v ? ids[b * T_ + t] : -1;
        lrr[tid] = v ? rr[(size_t)b * T_ + t] : 0.0f;
    }
    __syncthreads();

    {   // gather hidden0 -> fp8 LDS
        int c4 = tid & 127;
        float4 aw = *(const float4*)(aux_w + c4 * 4);
        float4 ab = *(const float4*)(aux_b + c4 * 4);
        int rbase = tid >> 7;
        for (int j = 0; j < 33; ++j) {
            int row = rbase + j * 2;
            int id = lid[row];
            int word = 0;
            if (id >= 0) {
                float vr = lrr[row];
                float4 e = *(const float4*)(emb + (size_t)id * D_ + c4 * 4);
                word = pk4fp8((e.x + vr * aw.x + ab.x) * SCALE_H0,
                              (e.y + vr * aw.y + ab.y) * SCALE_H0,
                              (e.z + vr * aw.z + ab.z) * SCALE_H0,
                              (e.w + vr * aw.w + ab.w) * SCALE_H0);
            }
            *(int*)(&H0s[row * H0S + c4 * 4]) = word;
        }
    }
    __syncthreads();

    unsigned char* Ob = H1buf + ((size_t)b * 2050 + 2 + r0) * 512;

    // one K-step of MFMAs against a loaded weight pair (FR0 = nt{0,1}, FR1 = nt{2,3})
#define CONV1_PHASE(FR0, FR1, SS)                                              \
    {   int k1 = (SS) >> 4, ci = (SS) & 15;                                    \
        _Pragma("unroll")                                                      \
        for (int mt = 0; mt < 4; ++mt) {                                       \
            long afr = *(const long*)(&H0s[(mt * 16 + m16 + k1) * H0S + ci * 32 + q * 8]); \
            acc[mt][0] = __builtin_amdgcn_mfma_f32_16x16x32_fp8_fp8(afr, FR0[0], acc[mt][0], 0, 0, 0); \
            acc[mt][1] = __builtin_amdgcn_mfma_f32_16x16x32_fp8_fp8(afr, FR0[1], acc[mt][1], 0, 0, 0); \
            acc[mt][2] = __builtin_amdgcn_mfma_f32_16x16x32_fp8_fp8(afr, FR1[0], acc[mt][2], 0, 0, 0); \
            acc[mt][3] = __builtin_amdgcn_mfma_f32_16x16x32_fp8_fp8(afr, FR1[1], acc[mt][3], 0, 0, 0); \
        } }

    #pragma unroll
    for (int nh = 0; nh < 2; ++nh) {
        floatx4 acc[4][4];
        #pragma unroll
        for (int i = 0; i < 4; ++i)
            #pragma unroll
            for (int j = 0; j < 4; ++j)
                acc[i][j] = (floatx4){0.f, 0.f, 0.f, 0.f};

        // pair-group bases: pg0 covers nt{0,1}, pg0+1 covers nt{2,3}
        const longx2* wp0 = (const longx2*)W1p
                          + ((size_t)(0 * 16 + nh * 8 + wave * 2 + 0) * 64 + lane);
        const longx2* wp1 = wp0 + 64;
        // K-step stride = 16 pair-groups * 64 lanes = 1024 longx2

        longx2 fA0 = wp0[0],                  fA1 = wp1[0];
        longx2 fB0 = wp0[(size_t)1 * 1024],   fB1 = wp1[(size_t)1 * 1024];
        longx2 fC0, fC1, fD0, fD1;

        #pragma unroll 1
        for (int s = 0; s < 48; s += 4) {
            fC0 = wp0[(size_t)(s + 2) * 1024]; fC1 = wp1[(size_t)(s + 2) * 1024];
            CONV1_PHASE(fA0, fA1, s)
            fD0 = wp0[(size_t)(s + 3) * 1024]; fD1 = wp1[(size_t)(s + 3) * 1024];
            CONV1_PHASE(fB0, fB1, s + 1)
            fA0 = wp0[(size_t)(s + 4) * 1024]; fA1 = wp1[(size_t)(s + 4) * 1024]; // pads at 48/49
            CONV1_PHASE(fC0, fC1, s + 2)
            fB0 = wp0[(size_t)(s + 5) * 1024]; fB1 = wp1[(size_t)(s + 5) * 1024];
            CONV1_PHASE(fD0, fD1, s + 3)
        }

        #pragma unroll
        for (int mt = 0; mt < 4; ++mt) {
            #pragma unroll
            for (int nt = 0; nt < 4; ++nt) {
                int col = nh * 256 + wave * 64 + nt * 16 + m16;
                float bsv = bias1[col];
                #pragma unroll
                for (int r = 0; r < 4; ++r) {
                    int row = mt * 16 + q * 4 + r;
                    float v = gelu_exact(acc[mt][nt][r] * INV1 + bsv) * SCALE_A;
                    Ob[(size_t)row * 512 + col] = f2fp8(v);
                }
            }
        }
    }
#undef CONV1_PHASE
}

// ---------------------------------------------------------------------------
// Kernel 3: conv2 (fp8 MFMA) + gelu + LN + masked column sums.
//   R8: conv1-clone K-loop (BM=64, two 256-col passes, acc[4][4], 2 streams,
//   depth-2 scalar rotation) with half-A parked in LDS (fp16, transposed
//   [256][68]) between passes instead of registers. This removes R6's aPk
//   (32 VGPR live across pass B = the spill trigger) while keeping the
//   K-loop at conv1's exact register profile (~76 VGPR + 64 AGPR) — the only
//   profile this compiler has kept the rotation alive in. Barrier after the
//   pass-A ds_writes prevents LDS->reg forwarding. LDS ~72 KB (>64 KB static
//   is fine on gfx950 — R3 ran 78 KB). LN/colsum epilogue reads half-A back
//   (own-thread ds_reads); colsum atomics issued directly (no colsum array).
//   FAIL LOG: R2 sunk, R3 regress, R4 spill, R5 sunk, R6 spill(aPk),
//   R7 spill(occupancy squeeze).
//   TRIPWIRE: WRITE_SIZE >> 6 MB => spill => revert to R5 133-us form and
//   accept plateau; dur > 134 us => hypothesis falsified => same revert.
// ---------------------------------------------------------------------------
#define H1S 520
#define HAT 68
__global__ __launch_bounds__(256, 2) void conv2ln_kernel(
    const unsigned char* __restrict__ H1buf, const unsigned char* __restrict__ W2p,
    const float* __restrict__ bias2,
    const float* __restrict__ ln_g, const float* __restrict__ ln_b,
    const float* __restrict__ maskp,
    float* __restrict__ psum, float* __restrict__ psumsq)
{
    __shared__ __align__(16) unsigned char H1s[66 * H1S];   // 34320 B
    __shared__ _Float16 halfAt[256 * HAT];                  // 34816 B (transposed)
    __shared__ float mrow[64];
    __shared__ float part[64][4][2];
    __shared__ float tot[64][2];
    // total ~72.1 KB -> 2 blocks/CU

    int tile = blockIdx.x;          // 0..31
    int b    = blockIdx.y;          // 0..31
    int r0   = tile << 6;           // output rows r0..r0+63
    int tid  = threadIdx.x;
    int wave = tid >> 6, lane = tid & 63;
    int q = lane >> 4, m16 = lane & 15;

    // stage H1 rows r0..r0+65 (2-row causal halo; H1buf rows pre-shifted +2)
    const unsigned char* src = H1buf + ((size_t)b * 2050 + r0) * 512;
    for (int g = tid; g < 66 * 32; g += 256) {
        int row = g >> 5, h = g & 31;
        *(float4*)(&H1s[row * H1S + h * 16]) = *(const float4*)(src + (size_t)row * 512 + h * 16);
    }
    if (tid < 64)
        mrow[tid] = clampf(maskp[(size_t)b * T_ + r0 + tid], 0.0f, 1.0f);
    __syncthreads();

#define C2_PHASE(FR0, FR1, SS)                                                 \
    {   int k2 = (SS) >> 4, ci = (SS) & 15;                                    \
        _Pragma("unroll")                                                      \
        for (int mt = 0; mt < 4; ++mt) {                                       \
            long afr = *(const long*)(&H1s[(mt * 16 + m16 + k2) * H1S + ci * 32 + q * 8]); \
            acc[mt][0] = __builtin_amdgcn_mfma_f32_16x16x32_fp8_fp8(afr, FR0[0], acc[mt][0], 0, 0, 0); \
            acc[mt][1] = __builtin_amdgcn_mfma_f32_16x16x32_fp8_fp8(afr, FR0[1], acc[mt][1], 0, 0, 0); \
            acc[mt][2] = __builtin_amdgcn_mfma_f32_16x16x32_fp8_fp8(afr, FR1[0], acc[mt][2], 0, 0, 0); \
            acc[mt][3] = __builtin_amdgcn_mfma_f32_16x16x32_fp8_fp8(afr, FR1[1], acc[mt][3], 0, 0, 0); \
        } }

    floatx4 acc[4][4];
    #pragma unroll
    for (int nh = 0; nh < 2; ++nh) {
        #pragma unroll
        for (int i = 0; i < 4; ++i)
            #pragma unroll
            for (int j = 0; j < 4; ++j)
                acc[i][j] = (floatx4){0.f, 0.f, 0.f, 0.f};

        const longx2* wp0 = (const longx2*)W2p
                          + ((size_t)(nh * 8 + wave * 2) * 64 + lane);
        const longx2* wp1 = wp0 + 64;
        // K-step stride = 16 pair-groups * 64 lanes = 1024 longx2

        longx2 fA0 = wp0[0],                  fA1 = wp1[0];
        longx2 fB0 = wp0[(size_t)1 * 1024],   fB1 = wp1[(size_t)1 * 1024];
        longx2 fC0, fC1, fD0, fD1;

        #pragma unroll 1
        for (int s = 0; s < 48; s += 4) {
            fC0 = wp0[(size_t)(s + 2) * 1024]; fC1 = wp1[(size_t)(s + 2) * 1024];
            C2_PHASE(fA0, fA1, s)
            fD0 = wp0[(size_t)(s + 3) * 1024]; fD1 = wp1[(size_t)(s + 3) * 1024];
            C2_PHASE(fB0, fB1, s + 1)
            fA0 = wp0[(size_t)(s + 4) * 1024]; fA1 = wp1[(size_t)(s + 4) * 1024]; // pads at 48/49
            C2_PHASE(fC0, fC1, s + 2)
            fB0 = wp0[(size_t)(s + 5) * 1024]; fB1 = wp1[(size_t)(s + 5) * 1024];
            C2_PHASE(fD0, fD1, s + 3)
        }

        if (nh == 0) {
            // pass-A epilogue: gelu -> fp16 -> LDS (transposed), then barrier
            // so the values cannot be register-forwarded across pass B.
            #pragma unroll
            for (int mt = 0; mt < 4; ++mt)
                #pragma unroll
                for (int nt = 0; nt < 4; ++nt) {
                    int col = wave * 64 + nt * 16 + m16;
                    float bsv = bias2[col];
                    #pragma unroll
                    for (int r = 0; r < 4; ++r) {
                        float g = gelu_exact(acc[mt][nt][r] * INV2 + bsv);
                        halfAt[col * HAT + (mt * 16 + q * 4 + r)] = (_Float16)g;
                    }
                }
            __syncthreads();
        } else {
            // pass-B epilogue: gelu in place (stays in acc)
            #pragma unroll
            for (int mt = 0; mt < 4; ++mt)
                #pragma unroll
                for (int nt = 0; nt < 4; ++nt) {
                    int col = 256 + wave * 64 + nt * 16 + m16;
                    float bsv = bias2[col];
                    #pragma unroll
                    for (int r = 0; r < 4; ++r)
                        acc[mt][nt][r] = gelu_exact(acc[mt][nt][r] * INV2 + bsv);
                }
        }
    }
#undef C2_PHASE

    // LN row stats over full 512-col rows: half-A from LDS, half-B from acc
    #pragma unroll
    for (int mt = 0; mt < 4; ++mt) {
        #pragma unroll
        for (int r = 0; r < 4; ++r) {
            float rs = 0.f, rq = 0.f;
            #pragma unroll
            for (int nt = 0; nt < 4; ++nt) {
                int colA = wave * 64 + nt * 16 + m16;
                float vA = (float)halfAt[colA * HAT + (mt * 16 + q * 4 + r)];
                float vB = acc[mt][nt][r];
                rs += vA + vB; rq += vA * vA + vB * vB;
            }
            rs += __shfl_xor(rs, 1);  rq += __shfl_xor(rq, 1);
            rs += __shfl_xor(rs, 2);  rq += __shfl_xor(rq, 2);
            rs += __shfl_xor(rs, 4);  rq += __shfl_xor(rq, 4);
            rs += __shfl_xor(rs, 8);  rq += __shfl_xor(rq, 8);
            if (m16 == 0) {
                int row = mt * 16 + q * 4 + r;
                part[row][wave][0] = rs;
                part[row][wave][1] = rq;
            }
        }
    }
    __syncthreads();
    if (tid < 128) {
        int row = tid >> 1, j = tid & 1;
        tot[row][j] = part[row][0][j] + part[row][1][j] + part[row][2][j] + part[row][3][j];
    }
    __syncthreads();

    float meanv[4][4], rstdv[4][4];
    #pragma unroll
    for (int mt = 0; mt < 4; ++mt)
        #pragma unroll
        for (int r = 0; r < 4; ++r) {
            int row = mt * 16 + q * 4 + r;
            float m = tot[row][0] * (1.0f / D_);
            float var = tot[row][1] * (1.0f / D_) - m * m;
            meanv[mt][r] = m;
            rstdv[mt][r] = rsqrtf((var > 0.0f ? var : 0.0f) + 1e-5f);
        }

    float csA[4], cqA[4], csB[4], cqB[4];
    float lgA[4], lbA[4], lgB[4], lbB[4];
    #pragma unroll
    for (int nt = 0; nt < 4; ++nt) {
        int colA = wave * 64 + nt * 16 + m16;
        lgA[nt] = ln_g[colA];       lbA[nt] = ln_b[colA];
        lgB[nt] = ln_g[colA + 256]; lbB[nt] = ln_b[colA + 256];
        csA[nt] = 0.f; cqA[nt] = 0.f; csB[nt] = 0.f; cqB[nt] = 0.f;
    }
    #pragma unroll
    for (int mt = 0; mt < 4; ++mt) {
        #pragma unroll
        for (int r = 0; r < 4; ++r) {
            int row = mt * 16 + q * 4 + r;
            float mk = mrow[row];
            float m = meanv[mt][r], rs = rstdv[mt][r];
            #pragma unroll
            for (int nt = 0; nt < 4; ++nt) {
                int colA = wave * 64 + nt * 16 + m16;
                float vA = (float)halfAt[colA * HAT + row];
                float vB = acc[mt][nt][r];
                float xnA = ((vA - m) * rs * lgA[nt] + lbA[nt]) * mk;
                float xnB = ((vB - m) * rs * lgB[nt] + lbB[nt]) * mk;
                csA[nt] += xnA; cqA[nt] += xnA * xnA;
                csB[nt] += xnB; cqB[nt] += xnB * xnB;
            }
        }
    }
    #pragma unroll
    for (int nt = 0; nt < 4; ++nt) {
        csA[nt] += __shfl_xor(csA[nt], 16);  cqA[nt] += __shfl_xor(cqA[nt], 16);
        csA[nt] += __shfl_xor(csA[nt], 32);  cqA[nt] += __shfl_xor(cqA[nt], 32);
        csB[nt] += __shfl_xor(csB[nt], 16);  cqB[nt] += __shfl_xor(cqB[nt], 16);
        csB[nt] += __shfl_xor(csB[nt], 32);  cqB[nt] += __shfl_xor(cqB[nt], 32);
    }
    if (lane < 16) {
        #pragma unroll
        for (int nt = 0; nt < 4; ++nt) {
            int colA = wave * 64 + nt * 16 + m16;
            atomicAdd(&psum[(size_t)b * D_ + colA],         csA[nt]);
            atomicAdd(&psumsq[(size_t)b * D_ + colA],       cqA[nt]);
            atomicAdd(&psum[(size_t)b * D_ + colA + 256],   csB[nt]);
            atomicAdd(&psumsq[(size_t)b * D_ + colA + 256], cqB[nt]);
        }
    }
}

// ---------------------------------------------------------------------------
// Kernels 4a/4b: MLP head. k-split x2 parallelism (grid y 8, thread pairs
//   split the dot-product, __shfl_xor(1) combine). mlp3 fused into mlp2 via
//   device-scope ticket counter (cnt_ws, re-zeroed in mlp1).
// ---------------------------------------------------------------------------
__global__ __launch_bounds__(128) void mlp1_kernel(
    const float* __restrict__ psum, const float* __restrict__ psumsq,
    const float* __restrict__ sup_ws,
    const float* __restrict__ p1w, const float* __restrict__ p1b,
    float* __restrict__ s1_ws, float* __restrict__ nrm_ws,
    int* __restrict__ cnt_ws)
{
    int b = blockIdx.x, jt = blockIdx.y;   // jt 0..7
    int tid = threadIdx.x;
    __shared__ float h[2 * D_];

    float n = sup_ws[b];
    float denom = (n > 1.0f) ? n : 1.0f;
    for (int i = tid; i < D_; i += 128) {
        float S = psum[(size_t)b * D_ + i];
        float Q = psumsq[(size_t)b * D_ + i];
        float mean = S / denom;
        float msum = Q - 2.0f * mean * S + n * mean * mean;
        float arg = msum / denom + 1e-6f;
        h[i] = mean;
        h[D_ + i] = sqrtf((arg > 0.0f) ? arg : 0.0f);
    }
    if (jt == 0 && tid == 0) { nrm_ws[b] = 0.0f; cnt_ws[b] = 0; }
    __syncthreads();

    int d  = jt * 64 + (tid >> 1);
    int kh = tid & 1;
    float z = (kh == 0) ? p1b[d] : 0.0f;
    const float4* w4 = (const float4*)(p1w + (size_t)d * (2 * D_) + kh * D_);
    const float*  hh = &h[kh * D_];
    for (int jj = 0; jj < D_ / 4; ++jj) {
        float4 wv = w4[jj];
        z += hh[jj * 4 + 0] * wv.x + hh[jj * 4 + 1] * wv.y
           + hh[jj * 4 + 2] * wv.z + hh[jj * 4 + 3] * wv.w;
    }
    z += __shfl_xor(z, 1);
    if (kh == 0) s1_ws[(size_t)b * D_ + d] = gelu_exact(z);
}

__global__ __launch_bounds__(128) void mlp2_kernel(
    const float* __restrict__ s1_ws, const float* __restrict__ sup_ws,
    const float* __restrict__ p2w, const float* __restrict__ p2b,
    float* __restrict__ nrm_ws, int* __restrict__ cnt_ws,
    float* __restrict__ out)
{
    int b = blockIdx.x, jt = blockIdx.y;   // jt 0..7
    int tid = threadIdx.x;
    __shared__ float s1[D_];
    __shared__ float red[128];

    for (int i = tid; i < D_; i += 128) s1[i] = s1_ws[(size_t)b * D_ + i];
    __syncthreads();

    int d  = jt * 64 + (tid >> 1);
    int kh = tid & 1;
    float z2 = (kh == 0) ? p2b[d] : 0.0f;
    const float4* w24 = (const float4*)(p2w + (size_t)d * D_ + kh * 256);
    const float*  ss  = &s1[kh * 256];
    for (int jj = 0; jj < 64; ++jj) {
        float4 wv = w24[jj];
        z2 += ss[jj * 4 + 0] * wv.x + ss[jj * 4 + 1] * wv.y
            + ss[jj * 4 + 2] * wv.z + ss[jj * 4 + 3] * wv.w;
    }
    z2 += __shfl_xor(z2, 1);
    float nsup = sup_ws[b];
    float st = tanhf(z2);
    if (!(nsup > 0.0f)) st = 0.0f;
    if (kh == 0) out[OFF1 + (size_t)b * D_ + d] = st;

    red[tid] = (kh == 0) ? st * st : 0.0f;
    __syncthreads();
    for (int s = 64; s > 0; s >>= 1) {
        if (tid < s) red[tid] += red[tid + s];
        __syncthreads();
    }
    if (tid == 0) {
        atomicAdd(&nrm_ws[b], red[0]);
        __threadfence();
        int old = atomicAdd(&cnt_ws[b], 1);
        if (old == 7) {
            float nv = atomicAdd(&nrm_ws[b], 0.0f);   // coherent read
            out[OFF10 + b] = sqrtf(nv);
        }
    }
}

// ---------------------------------------------------------------------------
extern "C" void kernel_launch(void* const* d_in, const int* in_sizes, int n_in,
                              void* d_out, int out_size, void* d_ws, size_t ws_size,
                              hipStream_t stream) {
    (void)in_sizes; (void)n_in; (void)out_size; (void)ws_size;
    const int*   unit_ids = (const int*)d_in[0];
    const float* dur      = (const float*)d_in[1];
    const float* mask     = (const float*)d_in[2];
    const float* emb      = (const float*)d_in[3];
    const float* aux_w    = (const float*)d_in[4];
    const float* aux_b    = (const float*)d_in[5];
    const float* conv1_w  = (const float*)d_in[6];
    const float* conv1_b  = (const float*)d_in[7];
    const float* conv2_w  = (const float*)d_in[8];
    const float* conv2_b  = (const float*)d_in[9];
    const float* ln_g     = (const float*)d_in[10];
    const float* ln_b     = (const float*)d_in[11];
    const float* p1_w     = (const float*)d_in[12];
    const float* p1_b     = (const float*)d_in[13];
    const float* p2_w     = (const float*)d_in[14];
    const float* p2_b     = (const float*)d_in[15];
    float* out = (float*)d_out;

    char* ws = (char*)d_ws;
    float*          rr     = (float*)(ws + WS_RR);
    float*          sup    = (float*)(ws + WS_SUP);
    float*          psum   = (float*)(ws + WS_PSUM);
    float*          psumsq = (float*)(ws + WS_PSUMSQ);
    unsigned char*  W1p    = (unsigned char*)(ws + WS_W1P);
    unsigned char*  W2p    = (unsigned char*)(ws + WS_W2P);
    unsigned char*  H1buf  = (unsigned char*)(ws + WS_H1);
    float*          s1_ws  = (float*)(ws + WS_S1);
    float*          nrm_ws = (float*)(ws + WS_NRM);
    int*            cnt_ws = (int*)(ws + WS_CNT);

    init_kernel<<<dim3(96), dim3(256), 0, stream>>>(
        dur, mask, conv1_w, conv2_w, W1p, W2p, H1buf, rr, sup, psum, out);
    conv1g_kernel<<<dim3(32, 32), dim3(256), 0, stream>>>(
        unit_ids, rr, emb, aux_w, aux_b, W1p, conv1_b, H1buf);
    conv2ln_kernel<<<dim3(32, 32), dim3(256), 0, stream>>>(
        H1buf, W2p, conv2_b, ln_g, ln_b, mask, psum, psumsq);
    mlp1_kernel<<<dim3(32, 8), dim3(128), 0, stream>>>(
        psum, psumsq, sup, p1_w, p1_b, s1_ws, nrm_ws, cnt_ws);
    mlp2_kernel<<<dim3(32, 8), dim3(128), 0, stream>>>(
        s1_ws, sup, p2_w, p2_b, nrm_ws, cnt_ws, out);
}

// Round 9
// 293.691 us; speedup vs baseline: 1.2882x; 1.0463x over previous
//
#include <hip/hip_runtime.h>
#include <hip/hip_bf16.h>
#include <math.h>

#define B_  32
#define T_  2048
#define D_  512
#define V_  1024
#define K_  3

typedef __attribute__((ext_vector_type(8))) short    short8;
typedef __attribute__((ext_vector_type(4))) float    floatx4;
typedef __attribute__((ext_vector_type(2))) long     longx2;   // 16 B paired fp8 frags

#define SCALE_H0 256.0f        // hidden0 fp8 scale (conv1 input)
#define SCALE_A  64.0f         // H1 activation fp8 scale (conv2 input)
#define SCALE_W  16.0f         // weight fp8 scale (both convs)
#define INV1 (1.0f/(SCALE_H0*SCALE_W))
#define INV2 (1.0f/(SCALE_A*SCALE_W))

// ---- output flat offsets (elements, fp32) ----
#define OFF0 0        // global_rate      [32]
#define OFF1 32       // summary_state    [32*512]
#define OFF2 16416    // residual_mean    [32]
#define OFF3 16448    // residual_var     [32]
#define OFF4 16480    // coverage         [32]
#define OFF5 16512    // mask             [32*2048]
#define OFF6 82048    // logdur           [32*2048]
#define OFF7 147584   // ref_residual     [32*2048]
#define OFF8 213120   // attn             [32*2048]
#define OFF9 278656   // prompt_role_fit  [32*2048]
#define OFF10 344192  // coeff_norm       [32]

// ---- workspace byte offsets (end 35,684,736 B < proven 36.34 MB) ----
// W1P/W2P are 48 K-steps * 16 KB + 2 PAD steps (32 KB) so the convs'
// branch-free depth-2 prefetch can over-read harmlessly.
#define WS_RR     0          // fp32 [32][2048]              262144 B
#define WS_SUP    262144     // fp32 [32]                       128 B
#define WS_PSUM   262272     // fp32 [32][512]                65536 B
#define WS_PSUMSQ 327808     // fp32 [32][512]                65536 B
#define WS_W1P    393344     // fp8 pair-packed conv1 w      819200 B (50 steps)
#define WS_W2P    1212544    // fp8 pair-packed conv2 w      819200 B (50 steps)
#define WS_H1     2031744    // fp8  [32][2050][512]       33587200 B
#define WS_S1     35618944   // fp32 [32][512] mlp hidden     65536 B
#define WS_NRM    35684480   // fp32 [32] coeff_norm accum      128 B
#define WS_CNT    35684608   // int  [32] mlp2 ticket           128 B

__device__ __forceinline__ float clampf(float v, float lo, float hi) {
    v = (v > lo) ? v : lo;
    return (v < hi) ? v : hi;
}
// NOTE: keep gelu_exact (erff) in the conv epilogues. The inlined tanh-form
// gelu_fast triggered accumulator spill-to-scratch in R8/R9/R10 (FETCH/WRITE
// blew up 10x, conv1g 130 -> 366 us). erff's call structure keeps acc
// register-resident. Do not "optimize" this again without checking WRITE_SIZE.
__device__ __forceinline__ float gelu_exact(float v) {
    return 0.5f * v * (1.0f + erff(v * 0.70710678118654752440f));
}
__device__ __forceinline__ unsigned char f2fp8(float x) {
    int v = __builtin_amdgcn_cvt_pk_fp8_f32(x, x, 0, false);
    return (unsigned char)(v & 0xFF);
}
__device__ __forceinline__ int pk4fp8(float a, float b, float c, float d) {
    int p0 = __builtin_amdgcn_cvt_pk_fp8_f32(a, b, 0, false);
    int p1 = __builtin_amdgcn_cvt_pk_fp8_f32(c, d, 0, false);
    return (p1 << 16) | (p0 & 0xFFFF);
}

__device__ __forceinline__ float block_reduce_sum(float v, float* red, int tid) {
    __syncthreads();
    red[tid] = v;
    __syncthreads();
    for (int s = 128; s > 0; s >>= 1) {
        if (tid < s) red[tid] += red[tid + s];
        __syncthreads();
    }
    float r = red[0];
    __syncthreads();
    return r;
}

// ---------------------------------------------------------------------------
// Kernel 1: MERGED init — blocks 0..31: per-batch stats (histogram-select
//   exact median + T-wise outputs); blocks 32..95: LDS-transpose weight
//   prepack (one weight matrix per block) + psum/H1-pad zeroing.
// Pair-packed weight layout: 16 B per (K-step s, pair-group pg, lane):
//   byte addr = ((s*16 + pg)*64 + lane)*16 + (ntg&1)*8, pg = ntg>>1.
// ---------------------------------------------------------------------------
#define NB 2048
#define HLO (-9.3f)
#define HSC ((float)NB / 10.05f)     // range [-9.3, 0.75]
#define WLS 1544                     // LDS row stride (1536 + 8 pad)
__global__ __launch_bounds__(256) void init_kernel(
    const float* __restrict__ dur, const float* __restrict__ maskp,
    const float* __restrict__ w1, const float* __restrict__ w2,
    unsigned char* __restrict__ W1p, unsigned char* __restrict__ W2p,
    unsigned char* __restrict__ H1buf,
    float* __restrict__ rr_ws, float* __restrict__ sup_ws,
    float* __restrict__ psum, float* __restrict__ out)
{
    int tid = threadIdx.x;

    if (blockIdx.x >= 32) {
        // ---------------- prepack part (LDS transpose) ----------------
        __shared__ unsigned char Wl[16 * WLS];       // 24704 B
        int pb  = blockIdx.x - 32;                   // 0..63
        int ws  = pb & 1;                            // 0 = w1, 1 = w2
        int ntg = pb >> 1;                           // 0..31 (16-col group)
        int lane = tid & 63, wave = tid >> 6;

        const float* wsrc = (ws ? w2 : w1) + (size_t)ntg * 16 * 1536;
        for (int i = tid; i < 6144; i += 256) {      // 16 cols x 1536 f
            float4 v = ((const float4*)wsrc)[i];
            int col_local = i / 384;                 // 384 float4 per col
            int pos = (i % 384) * 4;
            int word = pk4fp8(v.x * SCALE_W, v.y * SCALE_W,
                              v.z * SCALE_W, v.w * SCALE_W);
            *(int*)(&Wl[col_local * WLS + pos]) = word;
        }
        __syncthreads();

        int cl = lane & 15, qq = lane >> 4;
        int pg = ntg >> 1, half = ntg & 1;
        unsigned char* dst = ws ? W2p : W1p;
        for (int s = wave; s < 48; s += 4) {
            int ci = s & 15, k = s >> 4;
            const unsigned char* row = &Wl[cl * WLS];
            int kin = ci * 32 + qq * 8;
            unsigned char bb[8];
            #pragma unroll
            for (int e = 0; e < 8; ++e)
                bb[e] = row[(kin + e) * 3 + k];
            *(double*)(dst + (((size_t)(s * 16 + pg) * 64 + lane) * 16
                              + half * 8)) = *(double*)bb;
        }

        // zeroing: 64 blocks x 512 elems = 32768 elems each array
        #pragma unroll
        for (int j = 0; j < 2; ++j) {
            int idx = pb * 512 + j * 256 + tid;
            psum[idx] = 0.0f;                      // psum + psumsq contiguous
            int b = idx >> 10;
            int r = (idx >> 9) & 1;
            int d = idx & 511;
            H1buf[((size_t)b * 2050 + r) * 512 + d] = 0;
        }
        return;
    }

    // ---------------- stats part ----------------
    __shared__ int   hist[NB];
    __shared__ int   csum[256];
    __shared__ float red[256];
    __shared__ float cand[128];
    __shared__ float nsh, medsh;
    __shared__ int   sh_tb, sh_cb, sh_candn;

    int b = blockIdx.x;
    const float* durb = dur + (size_t)b * T_;
    const float* mkb  = maskp + (size_t)b * T_;

    float ld[8], mk[8];
    int   bn[8];
    float cnt = 0.0f;
    #pragma unroll
    for (int i = 0; i < 8; ++i) hist[tid * 8 + i] = 0;
    __syncthreads();
    #pragma unroll
    for (int i = 0; i < 8; ++i) {
        int t = tid + i * 256;
        float m = clampf(mkb[t], 0.0f, 1.0f);
        float dv = durb[t];
        dv = (dv >= 1e-4f) ? dv : 1e-4f;
        float l = logf(dv) * m;
        ld[i] = l; mk[i] = m;
        int bin = (int)((l - HLO) * HSC);
        bin = (bin < 0) ? 0 : ((bin > NB - 1) ? NB - 1 : bin);
        bn[i] = bin;
        if (m > 0.5f) { cnt += 1.0f; atomicAdd(&hist[bin], 1); }
    }
    float n = block_reduce_sum(cnt, red, tid);   // barriers make hist visible
    if (tid == 0) { nsh = n; sh_candn = 0; medsh = 0.0f; }

    // chunk sums + inclusive scan (Hillis-Steele)
    {
        int cs = 0;
        #pragma unroll
        for (int i = 0; i < 8; ++i) cs += hist[tid * 8 + i];
        csum[tid] = cs;
        __syncthreads();
        for (int off = 1; off < 256; off <<= 1) {
            int v = (tid >= off) ? csum[tid - off] : 0;
            __syncthreads();
            csum[tid] += v;
            __syncthreads();
        }
    }
    int ni = (int)(n + 0.5f);
    int k  = (ni > 0) ? ((ni - 1) >> 1) : 0;     // 0-indexed lower-median rank
    {
        int prevIncl = (tid > 0) ? csum[tid - 1] : 0;
        if (ni > 0 && k >= prevIncl && k < csum[tid]) {   // unique owner thread
            int cum = prevIncl, tb = tid * 8;
            #pragma unroll
            for (int i = 0; i < 8; ++i) {
                int c = hist[tid * 8 + i];
                if (k < cum + c) { tb = tid * 8 + i; break; }
                cum += c;
            }
            sh_tb = tb; sh_cb = cum;
        }
    }
    __syncthreads();
    // collect candidates in target bin
    if (ni > 0) {
        int tb = sh_tb;
        #pragma unroll
        for (int i = 0; i < 8; ++i) {
            if (mk[i] > 0.5f && bn[i] == tb) {
                int p = atomicAdd(&sh_candn, 1);
                if (p < 128) cand[p] = ld[i];
            }
        }
    }
    __syncthreads();
    if (tid == 0 && ni > 0) {
        int m = k - sh_cb;
        int cn = (sh_candn < 128) ? sh_candn : 128;
        float best = cand[0];
        for (int i = 0; i < cn; ++i) {
            int rank = 0;
            for (int j = 0; j < cn; ++j)
                rank += (cand[j] < cand[i]) || (cand[j] == cand[i] && j < i);
            if (rank == m) { best = cand[i]; break; }
        }
        medsh = best;
    }
    __syncthreads();
    float med = (ni > 0) ? medsh : 0.0f;
    med = clampf(med, -20.0f, 20.0f);

    float denom = (n > 1.0f) ? n : 1.0f;
    float rv[8];
    float ssum = 0.0f;
    #pragma unroll
    for (int i = 0; i < 8; ++i) { rv[i] = (ld[i] - med) * mk[i]; ssum += rv[i]; }
    float rsum = block_reduce_sum(ssum, red, tid);
    float rm = clampf(rsum / denom, -40.0f, 40.0f);

    float vsum_l = 0.0f;
    #pragma unroll
    for (int i = 0; i < 8; ++i) { float dd = rv[i] - rm; vsum_l += dd * dd * mk[i]; }
    float vsum = block_reduce_sum(vsum_l, red, tid);
    float var = clampf(vsum / denom, 1e-4f, 1e4f);

    float inv_sup = 1.0f / denom;
    #pragma unroll
    for (int i = 0; i < 8; ++i) {
        int t = tid + i * 256;
        size_t o = (size_t)b * T_ + t;
        out[OFF5 + o] = mk[i];
        out[OFF6 + o] = ld[i];
        out[OFF7 + o] = rv[i];
        out[OFF8 + o] = mk[i] * inv_sup;
        out[OFF9 + o] = rm * mk[i];
        rr_ws[o] = rv[i];
    }
    if (tid == 0) {
        out[OFF0 + b] = med;
        out[OFF2 + b] = rm;
        out[OFF3 + b] = var;
        float cov = n * (1.0f / (float)T_);
        out[OFF4 + b] = (cov > 0.05f) ? cov : 0.05f;
        sup_ws[b] = n;
    }
}

// ---------------------------------------------------------------------------
// Kernel 2: conv1 gather-GEMM, fp8 MFMA. BM=64 x 512 (two 256-col halves,
//   acc[4][4]). Pair-packed weights (one 16 B dwordx4 load covers two nt
//   fragments) + branch-free 4-phase register rotation, prefetch distance 2.
//   PROVEN R1: 195 -> ~58 us (~86% of the 50 us MFMA-issue floor).
//   launch_bounds MUST stay (256,3): (256,4) forces a 64-VGPR allocation
//   on this compiler (measured twice: R8, R12) -> accumulator spill ->
//   100+ MB scratch WRITE_SIZE, 2x slower. (256,3) = 76 VGPR, no scratch.
// ---------------------------------------------------------------------------
#define H0S 520
__global__ __launch_bounds__(256, 3) void conv1g_kernel(
    const int* __restrict__ ids, const float* __restrict__ rr,
    const float* __restrict__ emb,
    const float* __restrict__ aux_w, const float* __restrict__ aux_b,
    const unsigned char* __restrict__ W1p, const float* __restrict__ bias1,
    unsigned char* __restrict__ H1buf)
{
    __shared__ __align__(16) unsigned char H0s[66 * H0S];   // 34320 B
    __shared__ int   lid[66];
    __shared__ float lrr[66];

    int tile = blockIdx.x;          // 0..31
    int b    = blockIdx.y;          // 0..31
    int r0   = tile << 6;
    int tid  = threadIdx.x;
    int wave = tid >> 6, lane = tid & 63;
    int q = lane >> 4, m16 = lane & 15;

    if (tid < 66) {
        int t = r0 - 2 + tid;
        bool v = (t >= 0);
        lid[tid] = v ? ids[b * T_ + t] : -1;
        lrr[tid] = v ? rr[(size_t)b * T_ + t] : 0.0f;
    }
    __syncthreads();

    {   // gather hidden0 -> fp8 LDS
        int c4 = tid & 127;
        float4 aw = *(const float4*)(aux_w + c4 * 4);
        float4 ab = *(const float4*)(aux_b + c4 * 4);
        int rbase = tid >> 7;
        for (int j = 0; j < 33; ++j) {
            int row = rbase + j * 2;
            int id = lid[row];
            int word = 0;
            if (id >= 0) {
                float vr = lrr[row];
                float4 e = *(const float4*)(emb + (size_t)id * D_ + c4 * 4);
                word = pk4fp8((e.x + vr * aw.x + ab.x) * SCALE_H0,
                              (e.y + vr * aw.y + ab.y) * SCALE_H0,
                              (e.z + vr * aw.z + ab.z) * SCALE_H0,
                              (e.w + vr * aw.w + ab.w) * SCALE_H0);
            }
            *(int*)(&H0s[row * H0S + c4 * 4]) = word;
        }
    }
    __syncthreads();

    unsigned char* Ob = H1buf + ((size_t)b * 2050 + 2 + r0) * 512;

    // one K-step of MFMAs against a loaded weight pair (FR0 = nt{0,1}, FR1 = nt{2,3})
#define CONV1_PHASE(FR0, FR1, SS)                                              \
    {   int k1 = (SS) >> 4, ci = (SS) & 15;                                    \
        _Pragma("unroll")                                                      \
        for (int mt = 0; mt < 4; ++mt) {                                       \
            long afr = *(const long*)(&H0s[(mt * 16 + m16 + k1) * H0S + ci * 32 + q * 8]); \
            acc[mt][0] = __builtin_amdgcn_mfma_f32_16x16x32_fp8_fp8(afr, FR0[0], acc[mt][0], 0, 0, 0); \
            acc[mt][1] = __builtin_amdgcn_mfma_f32_16x16x32_fp8_fp8(afr, FR0[1], acc[mt][1], 0, 0, 0); \
            acc[mt][2] = __builtin_amdgcn_mfma_f32_16x16x32_fp8_fp8(afr, FR1[0], acc[mt][2], 0, 0, 0); \
            acc[mt][3] = __builtin_amdgcn_mfma_f32_16x16x32_fp8_fp8(afr, FR1[1], acc[mt][3], 0, 0, 0); \
        } }

    #pragma unroll
    for (int nh = 0; nh < 2; ++nh) {
        floatx4 acc[4][4];
        #pragma unroll
        for (int i = 0; i < 4; ++i)
            #pragma unroll
            for (int j = 0; j < 4; ++j)
                acc[i][j] = (floatx4){0.f, 0.f, 0.f, 0.f};

        // pair-group bases: pg0 covers nt{0,1}, pg0+1 covers nt{2,3}
        const longx2* wp0 = (const longx2*)W1p
                          + ((size_t)(0 * 16 + nh * 8 + wave * 2 + 0) * 64 + lane);
        const longx2* wp1 = wp0 + 64;
        // K-step stride = 16 pair-groups * 64 lanes = 1024 longx2

        longx2 fA0 = wp0[0],                  fA1 = wp1[0];
        longx2 fB0 = wp0[(size_t)1 * 1024],   fB1 = wp1[(size_t)1 * 1024];
        longx2 fC0, fC1, fD0, fD1;

        #pragma unroll 1
        for (int s = 0; s < 48; s += 4) {
            fC0 = wp0[(size_t)(s + 2) * 1024]; fC1 = wp1[(size_t)(s + 2) * 1024];
            CONV1_PHASE(fA0, fA1, s)
            fD0 = wp0[(size_t)(s + 3) * 1024]; fD1 = wp1[(size_t)(s + 3) * 1024];
            CONV1_PHASE(fB0, fB1, s + 1)
            fA0 = wp0[(size_t)(s + 4) * 1024]; fA1 = wp1[(size_t)(s + 4) * 1024]; // pads at 48/49
            CONV1_PHASE(fC0, fC1, s + 2)
            fB0 = wp0[(size_t)(s + 5) * 1024]; fB1 = wp1[(size_t)(s + 5) * 1024];
            CONV1_PHASE(fD0, fD1, s + 3)
        }

        #pragma unroll
        for (int mt = 0; mt < 4; ++mt) {
            #pragma unroll
            for (int nt = 0; nt < 4; ++nt) {
                int col = nh * 256 + wave * 64 + nt * 16 + m16;
                float bsv = bias1[col];
                #pragma unroll
                for (int r = 0; r < 4; ++r) {
                    int row = mt * 16 + q * 4 + r;
                    float v = gelu_exact(acc[mt][nt][r] * INV1 + bsv) * SCALE_A;
                    Ob[(size_t)row * 512 + col] = f2fp8(v);
                }
            }
        }
    }
#undef CONV1_PHASE
}

// ---------------------------------------------------------------------------
// Kernel 3: conv2 (fp8 MFMA) + gelu + LN + masked column sums.
//   R9: R8's proven structure (two 256-col passes, 2 streams, scalar depth-2
//   rotation, half-A parked in LDS fp16) at BM=32 so the footprint NATURALLY
//   fits 3 waves/SIMD: acc[2][4] = 32 AGPR, total regs ~140 <= (256,3)'s
//   ~170 cap (no squeeze — R7's mistake), LDS ~36 KB (H1s 34 rows 17.7 KB +
//   halfA [32][260] fp16 16.6 KB) -> 4 blocks LDS-wise, reg-limit 3 ->
//   3 blocks/CU = 3 waves/SIMD (+50% latency hiding vs R8's 2).
//   R8 counters motivating this: Occ 21%, VALUBusy 33% + MfmaUtil 36.5% —
//   latency/VALU serialization with no co-issue slack at 2 waves/SIMD.
//   Trade: per-phase MFMA cover halves (8 MFMA per 2x16B loads) — bet is
//   wave-level TLP more than compensates (conv1 runs 3/SIMD at 86%-of-floor).
//   FAIL LOG: R2 sunk, R3 regress, R4 spill, R5 sunk, R6 spill(aPk),
//   R7 spill(squeeze), R8 WIN (116 us).
//   TRIPWIRE: WRITE_SIZE >> 8 MB => spill => revert to R8 BM=64 form;
//   dur > 116 us => occupancy theory wrong => revert to R8.
// ---------------------------------------------------------------------------
#define H1S 520
#define HAC 260
__global__ __launch_bounds__(256, 3) void conv2ln_kernel(
    const unsigned char* __restrict__ H1buf, const unsigned char* __restrict__ W2p,
    const float* __restrict__ bias2,
    const float* __restrict__ ln_g, const float* __restrict__ ln_b,
    const float* __restrict__ maskp,
    float* __restrict__ psum, float* __restrict__ psumsq)
{
    __shared__ __align__(16) unsigned char H1s[34 * H1S];   // 17680 B
    __shared__ _Float16 halfA[32][HAC];                     // 16640 B
    __shared__ float mrow[32];
    __shared__ float part[32][4][2];
    __shared__ float tot[32][2];
    // total ~36 KB -> 4 blocks LDS-wise; regs cap at 3 -> 3 blocks/CU

    int tile = blockIdx.x;          // 0..63
    int b    = blockIdx.y;          // 0..31
    int r0   = tile << 5;           // output rows r0..r0+31
    int tid  = threadIdx.x;
    int wave = tid >> 6, lane = tid & 63;
    int q = lane >> 4, m16 = lane & 15;

    // stage H1 rows r0..r0+33 (2-row causal halo; H1buf rows pre-shifted +2)
    const unsigned char* src = H1buf + ((size_t)b * 2050 + r0) * 512;
    for (int g = tid; g < 34 * 32; g += 256) {
        int row = g >> 5, h = g & 31;
        *(float4*)(&H1s[row * H1S + h * 16]) = *(const float4*)(src + (size_t)row * 512 + h * 16);
    }
    if (tid < 32)
        mrow[tid] = clampf(maskp[(size_t)b * T_ + r0 + tid], 0.0f, 1.0f);
    __syncthreads();

#define C2_PHASE(FR0, FR1, SS)                                                 \
    {   int k2 = (SS) >> 4, ci = (SS) & 15;                                    \
        _Pragma("unroll")                                                      \
        for (int mt = 0; mt < 2; ++mt) {                                       \
            long afr = *(const long*)(&H1s[(mt * 16 + m16 + k2) * H1S + ci * 32 + q * 8]); \
            acc[mt][0] = __builtin_amdgcn_mfma_f32_16x16x32_fp8_fp8(afr, FR0[0], acc[mt][0], 0, 0, 0); \
            acc[mt][1] = __builtin_amdgcn_mfma_f32_16x16x32_fp8_fp8(afr, FR0[1], acc[mt][1], 0, 0, 0); \
            acc[mt][2] = __builtin_amdgcn_mfma_f32_16x16x32_fp8_fp8(afr, FR1[0], acc[mt][2], 0, 0, 0); \
            acc[mt][3] = __builtin_amdgcn_mfma_f32_16x16x32_fp8_fp8(afr, FR1[1], acc[mt][3], 0, 0, 0); \
        } }

    floatx4 acc[2][4];
    #pragma unroll
    for (int nh = 0; nh < 2; ++nh) {
        #pragma unroll
        for (int i = 0; i < 2; ++i)
            #pragma unroll
            for (int j = 0; j < 4; ++j)
                acc[i][j] = (floatx4){0.f, 0.f, 0.f, 0.f};

        const longx2* wp0 = (const longx2*)W2p
                          + ((size_t)(nh * 8 + wave * 2) * 64 + lane);
        const longx2* wp1 = wp0 + 64;
        // K-step stride = 16 pair-groups * 64 lanes = 1024 longx2

        longx2 fA0 = wp0[0],                  fA1 = wp1[0];
        longx2 fB0 = wp0[(size_t)1 * 1024],   fB1 = wp1[(size_t)1 * 1024];
        longx2 fC0, fC1, fD0, fD1;

        #pragma unroll 1
        for (int s = 0; s < 48; s += 4) {
            fC0 = wp0[(size_t)(s + 2) * 1024]; fC1 = wp1[(size_t)(s + 2) * 1024];
            C2_PHASE(fA0, fA1, s)
            fD0 = wp0[(size_t)(s + 3) * 1024]; fD1 = wp1[(size_t)(s + 3) * 1024];
            C2_PHASE(fB0, fB1, s + 1)
            fA0 = wp0[(size_t)(s + 4) * 1024]; fA1 = wp1[(size_t)(s + 4) * 1024]; // pads at 48/49
            C2_PHASE(fC0, fC1, s + 2)
            fB0 = wp0[(size_t)(s + 5) * 1024]; fB1 = wp1[(size_t)(s + 5) * 1024];
            C2_PHASE(fD0, fD1, s + 3)
        }

        if (nh == 0) {
            // pass-A epilogue: gelu -> fp16 -> LDS, then barrier so the
            // values cannot be register-forwarded across pass B.
            #pragma unroll
            for (int mt = 0; mt < 2; ++mt)
                #pragma unroll
                for (int nt = 0; nt < 4; ++nt) {
                    int col = wave * 64 + nt * 16 + m16;
                    float bsv = bias2[col];
                    #pragma unroll
                    for (int r = 0; r < 4; ++r) {
                        float g = gelu_exact(acc[mt][nt][r] * INV2 + bsv);
                        halfA[mt * 16 + q * 4 + r][col] = (_Float16)g;
                    }
                }
            __syncthreads();
        } else {
            // pass-B epilogue: gelu in place (stays in acc)
            #pragma unroll
            for (int mt = 0; mt < 2; ++mt)
                #pragma unroll
                for (int nt = 0; nt < 4; ++nt) {
                    int col = 256 + wave * 64 + nt * 16 + m16;
                    float bsv = bias2[col];
                    #pragma unroll
                    for (int r = 0; r < 4; ++r)
                        acc[mt][nt][r] = gelu_exact(acc[mt][nt][r] * INV2 + bsv);
                }
        }
    }
#undef C2_PHASE

    // LN row stats over full 512-col rows: half-A from LDS, half-B from acc
    #pragma unroll
    for (int mt = 0; mt < 2; ++mt) {
        #pragma unroll
        for (int r = 0; r < 4; ++r) {
            int row = mt * 16 + q * 4 + r;
            float rs = 0.f, rq = 0.f;
            #pragma unroll
            for (int nt = 0; nt < 4; ++nt) {
                int colA = wave * 64 + nt * 16 + m16;
                float vA = (float)halfA[row][colA];
                float vB = acc[mt][nt][r];
                rs += vA + vB; rq += vA * vA + vB * vB;
            }
            rs += __shfl_xor(rs, 1);  rq += __shfl_xor(rq, 1);
            rs += __shfl_xor(rs, 2);  rq += __shfl_xor(rq, 2);
            rs += __shfl_xor(rs, 4);  rq += __shfl_xor(rq, 4);
            rs += __shfl_xor(rs, 8);  rq += __shfl_xor(rq, 8);
            if (m16 == 0) {
                part[row][wave][0] = rs;
                part[row][wave][1] = rq;
            }
        }
    }
    __syncthreads();
    if (tid < 64) {
        int row = tid >> 1, j = tid & 1;
        tot[row][j] = part[row][0][j] + part[row][1][j] + part[row][2][j] + part[row][3][j];
    }
    __syncthreads();

    float meanv[2][4], rstdv[2][4];
    #pragma unroll
    for (int mt = 0; mt < 2; ++mt)
        #pragma unroll
        for (int r = 0; r < 4; ++r) {
            int row = mt * 16 + q * 4 + r;
            float m = tot[row][0] * (1.0f / D_);
            float var = tot[row][1] * (1.0f / D_) - m * m;
            meanv[mt][r] = m;
            rstdv[mt][r] = rsqrtf((var > 0.0f ? var : 0.0f) + 1e-5f);
        }

    float csA[4], cqA[4], csB[4], cqB[4];
    float lgA[4], lbA[4], lgB[4], lbB[4];
    #pragma unroll
    for (int nt = 0; nt < 4; ++nt) {
        int colA = wave * 64 + nt * 16 + m16;
        lgA[nt] = ln_g[colA];       lbA[nt] = ln_b[colA];
        lgB[nt] = ln_g[colA + 256]; lbB[nt] = ln_b[colA + 256];
        csA[nt] = 0.f; cqA[nt] = 0.f; csB[nt] = 0.f; cqB[nt] = 0.f;
    }
    #pragma unroll
    for (int mt = 0; mt < 2; ++mt) {
        #pragma unroll
        for (int r = 0; r < 4; ++r) {
            int row = mt * 16 + q * 4 + r;
            float mk = mrow[row];
            float m = meanv[mt][r], rs = rstdv[mt][r];
            #pragma unroll
            for (int nt = 0; nt < 4; ++nt) {
                int colA = wave * 64 + nt * 16 + m16;
                float vA = (float)halfA[row][colA];
                float vB = acc[mt][nt][r];
                float xnA = ((vA - m) * rs * lgA[nt] + lbA[nt]) * mk;
                float xnB = ((vB - m) * rs * lgB[nt] + lbB[nt]) * mk;
                csA[nt] += xnA; cqA[nt] += xnA * xnA;
                csB[nt] += xnB; cqB[nt] += xnB * xnB;
            }
        }
    }
    #pragma unroll
    for (int nt = 0; nt < 4; ++nt) {
        csA[nt] += __shfl_xor(csA[nt], 16);  cqA[nt] += __shfl_xor(cqA[nt], 16);
        csA[nt] += __shfl_xor(csA[nt], 32);  cqA[nt] += __shfl_xor(cqA[nt], 32);
        csB[nt] += __shfl_xor(csB[nt], 16);  cqB[nt] += __shfl_xor(cqB[nt], 16);
        csB[nt] += __shfl_xor(csB[nt], 32);  cqB[nt] += __shfl_xor(cqB[nt], 32);
    }
    if (lane < 16) {
        #pragma unroll
        for (int nt = 0; nt < 4; ++nt) {
            int colA = wave * 64 + nt * 16 + m16;
            atomicAdd(&psum[(size_t)b * D_ + colA],         csA[nt]);
            atomicAdd(&psumsq[(size_t)b * D_ + colA],       cqA[nt]);
            atomicAdd(&psum[(size_t)b * D_ + colA + 256],   csB[nt]);
            atomicAdd(&psumsq[(size_t)b * D_ + colA + 256], cqB[nt]);
        }
    }
}

// ---------------------------------------------------------------------------
// Kernels 4a/4b: MLP head. k-split x2 parallelism (grid y 8, thread pairs
//   split the dot-product, __shfl_xor(1) combine). mlp3 fused into mlp2 via
//   device-scope ticket counter (cnt_ws, re-zeroed in mlp1).
// ---------------------------------------------------------------------------
__global__ __launch_bounds__(128) void mlp1_kernel(
    const float* __restrict__ psum, const float* __restrict__ psumsq,
    const float* __restrict__ sup_ws,
    const float* __restrict__ p1w, const float* __restrict__ p1b,
    float* __restrict__ s1_ws, float* __restrict__ nrm_ws,
    int* __restrict__ cnt_ws)
{
    int b = blockIdx.x, jt = blockIdx.y;   // jt 0..7
    int tid = threadIdx.x;
    __shared__ float h[2 * D_];

    float n = sup_ws[b];
    float denom = (n > 1.0f) ? n : 1.0f;
    for (int i = tid; i < D_; i += 128) {
        float S = psum[(size_t)b * D_ + i];
        float Q = psumsq[(size_t)b * D_ + i];
        float mean = S / denom;
        float msum = Q - 2.0f * mean * S + n * mean * mean;
        float arg = msum / denom + 1e-6f;
        h[i] = mean;
        h[D_ + i] = sqrtf((arg > 0.0f) ? arg : 0.0f);
    }
    if (jt == 0 && tid == 0) { nrm_ws[b] = 0.0f; cnt_ws[b] = 0; }
    __syncthreads();

    int d  = jt * 64 + (tid >> 1);
    int kh = tid & 1;
    float z = (kh == 0) ? p1b[d] : 0.0f;
    const float4* w4 = (const float4*)(p1w + (size_t)d * (2 * D_) + kh * D_);
    const float*  hh = &h[kh * D_];
    for (int jj = 0; jj < D_ / 4; ++jj) {
        float4 wv = w4[jj];
        z += hh[jj * 4 + 0] * wv.x + hh[jj * 4 + 1] * wv.y
           + hh[jj * 4 + 2] * wv.z + hh[jj * 4 + 3] * wv.w;
    }
    z += __shfl_xor(z, 1);
    if (kh == 0) s1_ws[(size_t)b * D_ + d] = gelu_exact(z);
}

__global__ __launch_bounds__(128) void mlp2_kernel(
    const float* __restrict__ s1_ws, const float* __restrict__ sup_ws,
    const float* __restrict__ p2w, const float* __restrict__ p2b,
    float* __restrict__ nrm_ws, int* __restrict__ cnt_ws,
    float* __restrict__ out)
{
    int b = blockIdx.x, jt = blockIdx.y;   // jt 0..7
    int tid = threadIdx.x;
    __shared__ float s1[D_];
    __shared__ float red[128];

    for (int i = tid; i < D_; i += 128) s1[i] = s1_ws[(size_t)b * D_ + i];
    __syncthreads();

    int d  = jt * 64 + (tid >> 1);
    int kh = tid & 1;
    float z2 = (kh == 0) ? p2b[d] : 0.0f;
    const float4* w24 = (const float4*)(p2w + (size_t)d * D_ + kh * 256);
    const float*  ss  = &s1[kh * 256];
    for (int jj = 0; jj < 64; ++jj) {
        float4 wv = w24[jj];
        z2 += ss[jj * 4 + 0] * wv.x + ss[jj * 4 + 1] * wv.y
            + ss[jj * 4 + 2] * wv.z + ss[jj * 4 + 3] * wv.w;
    }
    z2 += __shfl_xor(z2, 1);
    float nsup = sup_ws[b];
    float st = tanhf(z2);
    if (!(nsup > 0.0f)) st = 0.0f;
    if (kh == 0) out[OFF1 + (size_t)b * D_ + d] = st;

    red[tid] = (kh == 0) ? st * st : 0.0f;
    __syncthreads();
    for (int s = 64; s > 0; s >>= 1) {
        if (tid < s) red[tid] += red[tid + s];
        __syncthreads();
    }
    if (tid == 0) {
        atomicAdd(&nrm_ws[b], red[0]);
        __threadfence();
        int old = atomicAdd(&cnt_ws[b], 1);
        if (old == 7) {
            float nv = atomicAdd(&nrm_ws[b], 0.0f);   // coherent read
            out[OFF10 + b] = sqrtf(nv);
        }
    }
}

// ---------------------------------------------------------------------------
extern "C" void kernel_launch(void* const* d_in, const int* in_sizes, int n_in,
                              void* d_out, int out_size, void* d_ws, size_t ws_size,
                              hipStream_t stream) {
    (void)in_sizes; (void)n_in; (void)out_size; (void)ws_size;
    const int*   unit_ids = (const int*)d_in[0];
    const float* dur      = (const float*)d_in[1];
    const float* mask     = (const float*)d_in[2];
    const float* emb      = (const float*)d_in[3];
    const float* aux_w    = (const float*)d_in[4];
    const float* aux_b    = (const float*)d_in[5];
    const float* conv1_w  = (const float*)d_in[6];
    const float* conv1_b  = (const float*)d_in[7];
    const float* conv2_w  = (const float*)d_in[8];
    const float* conv2_b  = (const float*)d_in[9];
    const float* ln_g     = (const float*)d_in[10];
    const float* ln_b     = (const float*)d_in[11];
    const float* p1_w     = (const float*)d_in[12];
    const float* p1_b     = (const float*)d_in[13];
    const float* p2_w     = (const float*)d_in[14];
    const float* p2_b     = (const float*)d_in[15];
    float* out = (float*)d_out;

    char* ws = (char*)d_ws;
    float*          rr     = (float*)(ws + WS_RR);
    float*          sup    = (float*)(ws + WS_SUP);
    float*          psum   = (float*)(ws + WS_PSUM);
    float*          psumsq = (float*)(ws + WS_PSUMSQ);
    unsigned char*  W1p    = (unsigned char*)(ws + WS_W1P);
    unsigned char*  W2p    = (unsigned char*)(ws + WS_W2P);
    unsigned char*  H1buf  = (unsigned char*)(ws + WS_H1);
    float*          s1_ws  = (float*)(ws + WS_S1);
    float*          nrm_ws = (float*)(ws + WS_NRM);
    int*            cnt_ws = (int*)(ws + WS_CNT);

    init_kernel<<<dim3(96), dim3(256), 0, stream>>>(
        dur, mask, conv1_w, conv2_w, W1p, W2p, H1buf, rr, sup, psum, out);
    conv1g_kernel<<<dim3(32, 32), dim3(256), 0, stream>>>(
        unit_ids, rr, emb, aux_w, aux_b, W1p, conv1_b, H1buf);
    conv2ln_kernel<<<dim3(64, 32), dim3(256), 0, stream>>>(
        H1buf, W2p, conv2_b, ln_g, ln_b, mask, psum, psumsq);
    mlp1_kernel<<<dim3(32, 8), dim3(128), 0, stream>>>(
        psum, psumsq, sup, p1_w, p1_b, s1_ws, nrm_ws, cnt_ws);
    mlp2_kernel<<<dim3(32, 8), dim3(128), 0, stream>>>(
        s1_ws, sup, p2_w, p2_b, nrm_ws, cnt_ws, out);
}